// Round 7
// baseline (1275.551 us; speedup 1.0000x reference)
//
#include <hip/hip_runtime.h>
#include <hip/hip_bf16.h>
#include <hip/hip_fp16.h>
#include <float.h>
#include <math.h>

#define DEVFN __device__ __forceinline__

// Compiler-only fence: wave64 executes DS ops in order; stops reordering.
DEVFN void wavefence() { __builtin_amdgcn_wave_barrier(); }

using half8 = __attribute__((ext_vector_type(8))) _Float16;
using f32x4 = __attribute__((ext_vector_type(4))) float;

namespace {
constexpr int Bq = 4, Nq = 8192, Cq = 32, Kq = 16;
constexpr int PTS = Bq * Nq;          // 32768 points
constexpr int CH = 16;                 // knn candidate chunks
constexpr int CAND = Nq / CH;          // 512 candidates per chunk
constexpr double ROWS = 524288.0;      // PTS * Kq

// dstat/bnp region bases (each region: [sum|mean x128][sumsq|scale x128])
constexpr int DS_Y = 0, DS_Z = 256, DS_G = 512, DS_H1 = 768, DS_H2 = 1024;

// ---- workspace layout (proven-available 228 MiB) ----
// time-disjoint: knn_d/kj [0,64) -> x0 [0,64) -> h1/h2 [0,32) (drb stage).
// x1 [64,128). enc [128,168) (written by encM, read by passA2s).
constexpr size_t OFF_KD   = 0;                          // knn_d 32MB
constexpr size_t OFF_KJ   = (size_t)32 << 20;           // knn_j 32MB
constexpr size_t OFF_X0   = 0;                          // x br0 f16 64MB
constexpr size_t OFF_X1   = (size_t)64 << 20;           // x br1 f16 64MB
constexpr size_t OFF_ENC  = (size_t)128 << 20;          // enc f16 [PTS][16][40] = 40MB
constexpr size_t OFF_H1   = 0;                          // h1 raw 16MB (x0 dead by drb)
constexpr size_t OFF_H2   = (size_t)16 << 20;           // h2 raw 16MB
constexpr size_t OFF_GRAW = (size_t)192 << 20;          // graw 16MB
constexpr size_t OFF_AGG  = (size_t)208 << 20;          // agg 16MB
constexpr size_t OFF_IDX  = (size_t)224 << 20;          // idx 2MB
constexpr size_t OFF_DST  = (size_t)226 << 20;          // dstat (1280 doubles)
constexpr size_t OFF_MST  = ((size_t)226 << 20) + 10240;
constexpr size_t OFF_BNP  = ((size_t)226 << 20) + 16384;
constexpr size_t WS_NEED  = ((size_t)226 << 20) + 32768;
// compact fallback layout (legacy path) for small workspaces
constexpr size_t FB_GRAW  = (size_t)64 << 20;
constexpr size_t FB_AGG   = (size_t)80 << 20;
constexpr size_t FB_H1    = (size_t)96 << 20;
constexpr size_t FB_H2    = (size_t)112 << 20;
constexpr size_t FB_IDX   = (size_t)128 << 20;
constexpr size_t FB_DST   = (size_t)130 << 20;
constexpr size_t FB_MST   = ((size_t)130 << 20) + 10240;
constexpr size_t FB_BNP   = ((size_t)130 << 20) + 16384;
}

// ---------------- KNN: batched bitonic top-16 ------------------------------
DEVFN void ce_asc(float& a, float& b) {
  const float lo = fminf(a, b), hi = fmaxf(a, b);
  a = lo; b = hi;
}

DEVFN void topk16_update(float* __restrict__ L, float* __restrict__ d) {
  // canonical ascending bitonic sort of d[0..15]
#pragma unroll
  for (int k = 2; k <= 16; k <<= 1) {
#pragma unroll
    for (int j = k >> 1; j > 0; j >>= 1) {
#pragma unroll
      for (int i = 0; i < 16; ++i) {
        const int l = i ^ j;
        if (l > i) {
          if ((i & k) == 0) {
            const float lo = fminf(d[i], d[l]), hi = fmaxf(d[i], d[l]);
            d[i] = lo; d[l] = hi;
          } else {
            const float lo = fminf(d[i], d[l]), hi = fmaxf(d[i], d[l]);
            d[i] = hi; d[l] = lo;
          }
        }
      }
    }
  }
  // fold: lowest-16 of L (asc) U d (asc) -> L bitonic
#pragma unroll
  for (int i = 0; i < 16; ++i) L[i] = fminf(L[i], d[15 - i]);
  // bitonic clean back to ascending
#pragma unroll
  for (int j = 8; j > 0; j >>= 1) {
#pragma unroll
    for (int i = 0; i < 16; ++i) {
      const int l = i ^ j;
      if (l > i) ce_asc(L[i], L[l]);
    }
  }
}

DEVFN float distf(const float4 c, const float qx, const float qy, const float qz) {
  const float dx = qx - c.x, dy = qy - c.y, dz = qz - c.z;
  return __fadd_rn(__fadd_rn(__fmul_rn(dx, dx), __fmul_rn(dy, dy)), __fmul_rn(dz, dz));
}

__global__ __launch_bounds__(256, 4) void knn_chunk_kernel(const float* __restrict__ xyz,
                                                           float* __restrict__ pd,
                                                           int* __restrict__ pj) {
  const int b = blockIdx.z;
  const int ch = blockIdx.y;
  const int n = blockIdx.x * 256 + threadIdx.x;
  __shared__ __align__(16) float4 tile[CAND];
  const float* xb = xyz + (size_t)b * Nq * 3;
  for (int t = threadIdx.x; t < CAND; t += 256) {
    const int j = ch * CAND + t;
    tile[t] = make_float4(xb[j * 3], xb[j * 3 + 1], xb[j * 3 + 2], 0.f);
  }
  __syncthreads();
  const float qx = xb[n * 3], qy = xb[n * 3 + 1], qz = xb[n * 3 + 2];
  float L[16];
#pragma unroll
  for (int i = 0; i < 16; ++i) L[i] = FLT_MAX;
  for (int t = 0; t < CAND; t += 16) {
    float d[16];
#pragma unroll
    for (int u = 0; u < 16; ++u) d[u] = distf(tile[t + u], qx, qy, qz);
    topk16_update(L, d);
  }
  const float kth = L[15];
  const size_t base = (((size_t)b * Nq + n) * CH + ch) * Kq;
  int cnt = 0, tfirst = -1;
  for (int t = 0; t < CAND; ++t) {
    const float d = distf(tile[t], qx, qy, qz);
    if (d < kth) { pd[base + cnt] = d; pj[base + cnt] = ch * CAND + t; ++cnt; }
    tfirst = (d == kth && tfirst < 0) ? t : tfirst;
  }
  if (cnt == 15) {  // typical (all-distinct): exactly one kth tie -> done
    pd[base + 15] = kth; pj[base + 15] = ch * CAND + tfirst; cnt = 16;
  }
  if (__any(cnt < 16)) {  // rare multi-tie fallback (exactness)
    for (int t = 0; t < CAND; ++t) {
      const float d = distf(tile[t], qx, qy, qz);
      if (d == kth && cnt < 16) { pd[base + cnt] = d; pj[base + cnt] = ch * CAND + t; ++cnt; }
    }
  }
}

__global__ __launch_bounds__(256, 4) void knn_merge_kernel(const float* __restrict__ pd,
                                                           const int* __restrict__ pj,
                                                           int* __restrict__ idxo) {
  const int q = blockIdx.x * 256 + threadIdx.x;
  const float* dp = pd + (size_t)q * CH * Kq;
  const int* jp = pj + (size_t)q * CH * Kq;
  float L[16];
#pragma unroll
  for (int i = 0; i < 16; ++i) L[i] = FLT_MAX;
  for (int t = 0; t < CH * Kq; t += 16) {
    float d[16];
#pragma unroll
    for (int u = 0; u < 16; u += 4) {
      const float4 v = *(const float4*)(dp + t + u);
      d[u] = v.x; d[u + 1] = v.y; d[u + 2] = v.z; d[u + 3] = v.w;
    }
    topk16_update(L, d);
  }
  const float kth = L[15];
  int* op = idxo + (size_t)q * Kq;
  int cnt = 0;
  for (int t = 0; t < CH * Kq; ++t) {
    const float d = dp[t];
    if (d < kth) { op[cnt] = jp[t]; ++cnt; }
  }
  for (int t = 0; t < CH * Kq; ++t) {
    const float d = dp[t];
    if (d == kth && cnt < 16) { op[cnt] = jp[t]; ++cnt; }
  }
}

// ---------------- gather pipeline pieces ------------------------------------
struct PF { float4 f0, f1; float nx, ny, nz; };

DEVFN PF issue_feat(const float* __restrict__ features, const float* __restrict__ xyz,
                    int p, int j, int sub) {
  const int b = p >> 13;
  const float* fr = features + ((size_t)b * Nq + j) * Cq;
  const float* xb = xyz + ((size_t)b * Nq + j) * 3;
  PF r;
  r.f0 = *(const float4*)(fr + sub * 8);
  r.f1 = *(const float4*)(fr + sub * 8 + 4);
  r.nx = xb[0]; r.ny = xb[1]; r.nz = xb[2];
  return r;
}

DEVFN int issue_idx(const int* __restrict__ idx, int p, int lane) {
  return idx[(size_t)p * Kq + (lane >> 2)];
}

DEVFN float3 issue_query(const float* __restrict__ xyz, int p) {
  const float* q = xyz + (size_t)p * 3;  // [B,N,3] flat: p = b*Nq+n
  return make_float3(q[0], q[1], q[2]);
}

// legacy enc row layout (f16, STORED-space, 40h = 80B/row)
DEVFN void commit_enc(__half* __restrict__ enc, int lane, const PF& pf,
                      float qx, float qy, float qz) {
  const int k = lane >> 2, sub = lane & 3;
  __half* er = enc + k * 40;
  union { float4 f; __half2 h[4]; } u;
  u.h[0] = __floats2half2_rn(pf.f0.x, pf.f0.y);
  u.h[1] = __floats2half2_rn(pf.f0.z, pf.f0.w);
  u.h[2] = __floats2half2_rn(pf.f1.x, pf.f1.y);
  u.h[3] = __floats2half2_rn(pf.f1.z, pf.f1.w);
  *(float4*)(er + sub * 8) = u.f;    // byte 80k+16*sub: 16B aligned
  if (sub == 0) {
    const float rx = pf.nx - qx, ry = pf.ny - qy, rz = pf.nz - qz;
    const float ss = rx * rx + ry * ry + rz * rz;
    const float dd = sqrtf(fmaxf(ss, 1e-12f));
    __half2* rd = (__half2*)(er + 32);
    rd[0] = __floats2half2_rn(rx, ry);
    rd[1] = __floats2half2_rn(rz, dd);
  }
}

// zero the 4 pad halves of each of the wave's 16 rows (legacy 40h layout).
DEVFN void zero_enc_pad(__half* __restrict__ enc, int lane) {
  if (lane < 16) {
    const __half2 z2 = __floats2half2_rn(0.f, 0.f);
    __half2* pz = (__half2*)(enc + lane * 40 + 36);
    pz[0] = z2; pz[1] = z2;
  }
}

// dot(enc_row (40 f16), wh2[20]) -- legacy fallback path.
DEVFN float dot40h(const __half* __restrict__ er, const __half2* __restrict__ wh2) {
  float a0 = 0.f, a1 = 0.f, a2 = 0.f, a3 = 0.f;
#pragma unroll
  for (int r = 0; r < 5; ++r) {
    union { float4 f; __half2 h[4]; } u;
    u.f = *(const float4*)(er + r * 8);
#pragma unroll
    for (int q = 0; q < 4; ++q) {
      const __half2 xv = u.h[q];
      const __half2 wv = wh2[r * 4 + q];
      if (q & 1) {
        a2 += __low2float(xv) * __low2float(wv);
        a3 += __high2float(xv) * __high2float(wv);
      } else {
        a0 += __low2float(xv) * __low2float(wv);
        a1 += __high2float(xv) * __high2float(wv);
      }
    }
  }
  return (a0 + a1) + (a2 + a3);
}

// dot(x_row (64 f16), sh2[32]) -- legacy fallback path.
DEVFN float dot64x(const __half* __restrict__ xr, const __half2* __restrict__ sh2) {
  float a0 = 0.f, a1 = 0.f, a2 = 0.f, a3 = 0.f;
#pragma unroll
  for (int r = 0; r < 8; ++r) {
    union { float4 f; __half2 h[4]; } u;
    u.f = *(const float4*)(xr + r * 8);
#pragma unroll
    for (int q = 0; q < 4; ++q) {
      const __half2 xv = u.h[q];
      const __half2 wv = sh2[r * 4 + q];
      if (q & 1) {
        a2 += __low2float(xv) * __low2float(wv);
        a3 += __high2float(xv) * __high2float(wv);
      } else {
        a0 += __low2float(xv) * __low2float(wv);
        a1 += __high2float(xv) * __high2float(wv);
      }
    }
  }
  return (a0 + a1) + (a2 + a3);
}

// load lane's 36 weights (original order) into STORED-space f16 pairs.
DEVFN void load_w40(const float* __restrict__ Wrow, __half2* wh2) {
#pragma unroll
  for (int c = 0; c < 16; ++c)
    wh2[c] = __floats2half2_rn(Wrow[4 + 2 * c], Wrow[5 + 2 * c]);
  wh2[16] = __floats2half2_rn(Wrow[0], Wrow[1]);
  wh2[17] = __floats2half2_rn(Wrow[2], Wrow[3]);
  wh2[18] = __floats2half2_rn(0.f, 0.f);
  wh2[19] = wh2[18];
}

// MFMA B-fragments. B[k][n] layout: col n = lane&15 (+tile*16),
// k = (lane>>4)*8 + j (+kstep*32). Layer1: k = STORED enc dim (pad>=36 zero).
DEVFN void load_b1(const float* __restrict__ W, int lane, half8* b1) {
  const int o16 = lane & 15, q = lane >> 4;
#pragma unroll
  for (int t = 0; t < 4; ++t) {
    const int o = t * 16 + o16;
#pragma unroll
    for (int ks = 0; ks < 2; ++ks) {
      half8 v;
#pragma unroll
      for (int j = 0; j < 8; ++j) {
        const int s = ks * 32 + q * 8 + j;
        float wv = 0.f;
        if (s < 36) { const int orig = (s < 32) ? (s + 4) : (s - 32); wv = W[o * 36 + orig]; }
        v[j] = (_Float16)wv;
      }
      b1[t * 2 + ks] = v;
    }
  }
}

DEVFN void load_b2(const float* __restrict__ S1, int lane, half8* b2) {
  const int o16 = lane & 15, q = lane >> 4;
#pragma unroll
  for (int t = 0; t < 4; ++t) {
    const int o = t * 16 + o16;
#pragma unroll
    for (int ks = 0; ks < 2; ++ks) {
      half8 v;
#pragma unroll
      for (int j = 0; j < 8; ++j) {
        const int c = ks * 32 + q * 8 + j;
        v[j] = (_Float16)S1[o * 64 + c];
      }
      b2[t * 2 + ks] = v;
    }
  }
}

// pipeline open/close macros (body sits between them as ordinary code).
#define GATHER_PROLOGUE                                                      \
  int p = wid;                                                               \
  int jc = issue_idx(idx, p, lane);                                          \
  PF cur = issue_feat(features, xyz, p, jc, lane & 3);                       \
  float3 qc = issue_query(xyz, p);                                           \
  int pn0 = p + nw; if (pn0 >= PTS) pn0 = p;                                 \
  int jn = issue_idx(idx, pn0, lane);                                        \
  float3 qn = issue_query(xyz, pn0);                                         \
  for (; p < PTS; p += nw) {                                                 \
    int pn = p + nw; if (pn >= PTS) pn = p;                                  \
    int pn2 = pn + nw; if (pn2 >= PTS) pn2 = pn;                             \
    PF nxt = issue_feat(features, xyz, pn, jn, lane & 3);                    \
    const int jn2 = issue_idx(idx, pn2, lane);                               \
    const float3 q2 = issue_query(xyz, pn2);                                 \
    commit_enc(enc, lane, cur, qc.x, qc.y, qc.z);                            \
    wavefence();

#define GATHER_EPILOGUE                                                      \
    wavefence();                                                             \
    cur = nxt; qc = qn; qn = q2; jn = jn2;                                   \
  }

// ---------------- encM: moments + (mat path) enc copy-out -------------------
// M = sum enc^T enc (36x36 STORED-space), v = sum enc. When encb != nullptr,
// also streams each point's 16x40h enc rows (1280B, byte-linear) to global
// so passA2s never re-gathers.
__global__ __launch_bounds__(256) void encM_kernel(const float* __restrict__ xyz,
                                                   const float* __restrict__ features,
                                                   const int* __restrict__ idx,
                                                   float* __restrict__ mstat,
                                                   __half* __restrict__ encb) {
  __shared__ __align__(16) __half encS[4][16 * 40];
  __shared__ float mred[4][36 * 37];
  const int lane = threadIdx.x & 63, wv = threadIdx.x >> 6;
  __half* enc = encS[wv];
  zero_enc_pad(enc, lane);
  wavefence();
  const int li = (lane < 36) ? lane : 0;  // clamp: lanes>=36 compute junk, never stored
  float macc[36];
#pragma unroll
  for (int i = 0; i < 36; ++i) macc[i] = 0.f;
  float vacc = 0.f;
  const int wid = blockIdx.x * 4 + wv, nw = gridDim.x * 4;
  GATHER_PROLOGUE
#pragma unroll
    for (int k = 0; k < 16; ++k) {
      const __half* er = enc + k * 40;
      const float ei = __half2float(er[li]);
      vacc += ei;
#pragma unroll
      for (int r = 0; r < 5; ++r) {
        union { float4 f; __half2 h[4]; } u;
        u.f = *(const float4*)(er + r * 8);
#pragma unroll
        for (int q = 0; q < 4; ++q) {
          const int s = r * 8 + 2 * q;
          if (s < 36)     macc[s]     += ei * __low2float(u.h[q]);
          if (s + 1 < 36) macc[s + 1] += ei * __high2float(u.h[q]);
        }
      }
    }
    if (encb) {  // 1280B linear copy: LDS byte c*16 -> global p*1280 + c*16
#pragma unroll
      for (int it = 0; it < 2; ++it) {
        const int c = it * 64 + lane;
        if (c < 80) {
          const float4 v = *(const float4*)((const char*)enc + c * 16);
          *(float4*)((char*)encb + (size_t)p * 1280 + c * 16) = v;
        }
      }
    }
  GATHER_EPILOGUE
  if (lane < 36) {
#pragma unroll
    for (int j = 0; j < 36; ++j) mred[wv][lane * 37 + j] = macc[j];
    mred[wv][lane * 37 + 36] = vacc;
  }
  __syncthreads();
  for (int t = threadIdx.x; t < 36 * 37; t += 256) {
    const float s = mred[0][t] + mred[1][t] + mred[2][t] + mred[3][t];
    atomicAdd(&mstat[t], s);
  }
}

// y-stat finalize from STORED-space moments.
__global__ void y_finalize_kernel(const float* __restrict__ mstat,
                                  const float* __restrict__ wl1,
                                  const float* __restrict__ wl2,
                                  float* __restrict__ bnp) {
  const int t = threadIdx.x;  // 128
  const int br = t >> 6, o = t & 63;
  const float* W = br ? wl2 : wl1;
  double wrow[36];
  for (int s = 0; s < 36; ++s) {
    const int orig = (s < 32) ? (s + 4) : (s - 32);
    wrow[s] = (double)W[o * 36 + orig];
  }
  double mean = 0.0, ey2 = 0.0;
  for (int i = 0; i < 36; ++i) {
    mean += wrow[i] * (double)mstat[i * 37 + 36];
    double rowacc = 0.0;
    for (int j = 0; j < 36; ++j) rowacc += wrow[j] * (double)mstat[i * 37 + j];
    ey2 += wrow[i] * rowacc;
  }
  const double invR = 1.0 / ROWS;
  mean *= invR; ey2 *= invR;
  const double var = ey2 - mean * mean;
  bnp[DS_Y + br * 64 + o] = (float)mean;
  bnp[DS_Y + 128 + br * 64 + o] = (float)(1.0 / sqrt(var + 1e-5));
}

// ---------------- generic BN stat finalize: mean + rsqrt(var+eps) -----------
__global__ void bn_finalize_kernel(const double* __restrict__ dstat, float* __restrict__ bnp,
                                   int base, double invc) {
  const int t = threadIdx.x;  // 128 threads
  const double m = dstat[base + t] * invc;
  const double v = dstat[base + 128 + t] * invc - m * m;
  bnp[base + t] = (float)m;
  bnp[base + 128 + t] = (float)(1.0 / sqrt(v + 1e-5));
}

// ---------------- passA2s (streaming): enc -> y (MFMA, both br) -> x0,x1 ----
// Reads enc from global ([PTS][16][40]h). A-frag a0 = cols q4*8..+8 (always
// < 32); a1 = cols 32+q4*8..+8: q4==0 -> rel/dist+pads, q4>0 -> zeros
// (bitwise identical to the zero-padded 64-col enc of the gather version).
__global__ __launch_bounds__(256)
void passA2s_kernel(const __half* __restrict__ encbuf,
                    const float* __restrict__ wl1,
                    const float* __restrict__ wl2,
                    const float* __restrict__ bnp,
                    __half* __restrict__ x0buf,
                    __half* __restrict__ x1buf) {
  __shared__ __align__(16) __half xS[4][16 * 64];
  const int lane = threadIdx.x & 63, wv = threadIdx.x >> 6;
  __half* xL = xS[wv];
  half8 b1a[8], b1b[8];
  load_b1(wl1, lane, b1a);
  load_b1(wl2, lane, b1b);
  const int r16 = lane & 15, q4 = lane >> 4;
  float ym0[4], ys0[4], ym1[4], ys1[4];
#pragma unroll
  for (int t = 0; t < 4; ++t) {
    ym0[t] = bnp[DS_Y + t * 16 + r16];
    ys0[t] = bnp[DS_Y + 128 + t * 16 + r16];
    ym1[t] = bnp[DS_Y + 64 + t * 16 + r16];
    ys1[t] = bnp[DS_Y + 128 + 64 + t * 16 + r16];
  }
  const int wid = blockIdx.x * 4 + wv, nw = gridDim.x * 4;
  for (int p = wid; p < PTS; p += nw) {
    const size_t eb = (size_t)p * 640 + r16 * 40 + q4 * 8;
    const half8 a0 = *(const half8*)(encbuf + eb);
    half8 a1;
#pragma unroll
    for (int j = 0; j < 8; ++j) a1[j] = (_Float16)0.f;
    if (q4 == 0) a1 = *(const half8*)(encbuf + eb + 32);
    // ---- branch 0 ----
    {
      f32x4 yt[4];
#pragma unroll
      for (int t = 0; t < 4; ++t) {
        f32x4 acc = {0.f, 0.f, 0.f, 0.f};
        acc = __builtin_amdgcn_mfma_f32_16x16x32_f16(a0, b1a[t * 2], acc, 0, 0, 0);
        acc = __builtin_amdgcn_mfma_f32_16x16x32_f16(a1, b1a[t * 2 + 1], acc, 0, 0, 0);
        yt[t] = acc;
      }
#pragma unroll
      for (int t = 0; t < 4; ++t) {
        const int col = t * 16 + r16;
        const int chk = col >> 3;
#pragma unroll
        for (int rr = 0; rr < 4; ++rr) {
          const int row = q4 * 4 + rr;
          float xv = (yt[t][rr] - ym0[t]) * ys0[t];
          xv = xv > 0.f ? xv : 0.f;
          *(_Float16*)((char*)xL + row * 128 + ((chk ^ (row & 7)) * 16) + (col & 7) * 2) =
              (_Float16)xv;
        }
      }
      wavefence();
#pragma unroll
      for (int it = 0; it < 2; ++it) {
        const int chunk = it * 64 + lane;
        const int row = chunk >> 3, c8 = chunk & 7;
        const float4 xv4 = *(const float4*)((const char*)xL + row * 128 + ((c8 ^ (row & 7)) * 16));
        *(float4*)((char*)x0buf + (size_t)p * 2048 + chunk * 16) = xv4;
      }
      wavefence();   // copyout read done before br1 overwrites xL
    }
    // ---- branch 1 ----
    {
      f32x4 yt[4];
#pragma unroll
      for (int t = 0; t < 4; ++t) {
        f32x4 acc = {0.f, 0.f, 0.f, 0.f};
        acc = __builtin_amdgcn_mfma_f32_16x16x32_f16(a0, b1b[t * 2], acc, 0, 0, 0);
        acc = __builtin_amdgcn_mfma_f32_16x16x32_f16(a1, b1b[t * 2 + 1], acc, 0, 0, 0);
        yt[t] = acc;
      }
#pragma unroll
      for (int t = 0; t < 4; ++t) {
        const int col = t * 16 + r16;
        const int chk = col >> 3;
#pragma unroll
        for (int rr = 0; rr < 4; ++rr) {
          const int row = q4 * 4 + rr;
          float xv = (yt[t][rr] - ym1[t]) * ys1[t];
          xv = xv > 0.f ? xv : 0.f;
          *(_Float16*)((char*)xL + row * 128 + ((chk ^ (row & 7)) * 16) + (col & 7) * 2) =
              (_Float16)xv;
        }
      }
      wavefence();
#pragma unroll
      for (int it = 0; it < 2; ++it) {
        const int chunk = it * 64 + lane;
        const int row = chunk >> 3, c8 = chunk & 7;
        const float4 xv4 = *(const float4*)((const char*)xL + row * 128 + ((c8 ^ (row & 7)) * 16));
        *(float4*)((char*)x1buf + (size_t)p * 2048 + chunk * 16) = xv4;
      }
      wavefence();   // xL reuse next iteration
    }
  }
}

// ---------------- zstat: z = x @ S1^T via MFMA, accumulate BN stats ---------
// z bits == what passB2 will recompute (same f16 x, same MFMA) == old z.
__global__ __launch_bounds__(256)
void zstat_kernel(const __half* __restrict__ x0, const __half* __restrict__ x1,
                  const float* __restrict__ s1a, const float* __restrict__ s1b,
                  double* __restrict__ dstat) {
  const int lane = threadIdx.x & 63, wv = threadIdx.x >> 6;
  half8 b2a[8], b2b[8];
  load_b2(s1a, lane, b2a);
  load_b2(s1b, lane, b2b);
  const int r16 = lane & 15, q4 = lane >> 4;
  float sa1[4] = {0.f, 0.f, 0.f, 0.f}, sa2[4] = {0.f, 0.f, 0.f, 0.f};
  float sb1[4] = {0.f, 0.f, 0.f, 0.f}, sb2s[4] = {0.f, 0.f, 0.f, 0.f};
  const int wid = blockIdx.x * 4 + wv, nw = gridDim.x * 4;
  for (int p = wid; p < PTS; p += nw) {
    const size_t abase = (size_t)p * 1024 + r16 * 64 + q4 * 8;
    const half8 xa0 = *(const half8*)(x0 + abase);
    const half8 xa1 = *(const half8*)(x0 + abase + 32);
    const half8 xb0 = *(const half8*)(x1 + abase);
    const half8 xb1 = *(const half8*)(x1 + abase + 32);
#pragma unroll
    for (int t = 0; t < 4; ++t) {
      f32x4 acc = {0.f, 0.f, 0.f, 0.f};
      acc = __builtin_amdgcn_mfma_f32_16x16x32_f16(xa0, b2a[t * 2], acc, 0, 0, 0);
      acc = __builtin_amdgcn_mfma_f32_16x16x32_f16(xa1, b2a[t * 2 + 1], acc, 0, 0, 0);
#pragma unroll
      for (int rr = 0; rr < 4; ++rr) { const float zv = acc[rr]; sa1[t] += zv; sa2[t] += zv * zv; }
      f32x4 acc2 = {0.f, 0.f, 0.f, 0.f};
      acc2 = __builtin_amdgcn_mfma_f32_16x16x32_f16(xb0, b2b[t * 2], acc2, 0, 0, 0);
      acc2 = __builtin_amdgcn_mfma_f32_16x16x32_f16(xb1, b2b[t * 2 + 1], acc2, 0, 0, 0);
#pragma unroll
      for (int rr = 0; rr < 4; ++rr) { const float zv = acc2[rr]; sb1[t] += zv; sb2s[t] += zv * zv; }
    }
  }
#pragma unroll
  for (int t = 0; t < 4; ++t) {
    sa1[t] += __shfl_xor(sa1[t], 16, 64);  sa1[t] += __shfl_xor(sa1[t], 32, 64);
    sa2[t] += __shfl_xor(sa2[t], 16, 64);  sa2[t] += __shfl_xor(sa2[t], 32, 64);
    sb1[t] += __shfl_xor(sb1[t], 16, 64);  sb1[t] += __shfl_xor(sb1[t], 32, 64);
    sb2s[t] += __shfl_xor(sb2s[t], 16, 64); sb2s[t] += __shfl_xor(sb2s[t], 32, 64);
  }
  if (lane < 16) {
#pragma unroll
    for (int t = 0; t < 4; ++t) {
      atomicAdd(&dstat[DS_Z + t * 16 + lane], (double)sa1[t]);
      atomicAdd(&dstat[DS_Z + 128 + t * 16 + lane], (double)sa2[t]);
      atomicAdd(&dstat[DS_Z + 64 + t * 16 + lane], (double)sb1[t]);
      atomicAdd(&dstat[DS_Z + 128 + 64 + t * 16 + lane], (double)sb2s[t]);
    }
  }
}

// ---------------- passB2: read x, recompute z via MFMA -> LDS, then softmax -
__global__ __launch_bounds__(256)
void passB2_mat_kernel(const __half* __restrict__ xbuf,
                       const float* __restrict__ S1,
                       const float* __restrict__ s2,
                       const float* __restrict__ sb,
                       const float* __restrict__ mw,
                       const float* __restrict__ bnp,
                       double* __restrict__ dstat,
                       float* __restrict__ graw,
                       int br) {
  __shared__ __align__(16) __half2 mwl2[64 * 34];  // row stride 34 pairs
  __shared__ __align__(16) float featL[4][64];
  __shared__ __align__(16) float zS[4][16 * 64];
  for (int t = threadIdx.x; t < 64 * 32; t += 256) {
    const int r = t >> 5, c2 = t & 31;
    mwl2[r * 34 + c2] = __floats2half2_rn(mw[r * 64 + c2 * 2], mw[r * 64 + c2 * 2 + 1]);
  }
  __syncthreads();  // one-time weight staging only
  const int lane = threadIdx.x & 63, wv = threadIdx.x >> 6;
  const int r16 = lane & 15, q4 = lane >> 4;
  half8 b2[8];
  load_b2(S1, lane, b2);
  const __half2* mrow = mwl2 + lane * 34;
  const float zm = bnp[DS_Z + br * 64 + lane];
  const float zsc = bnp[DS_Z + 128 + br * 64 + lane];
  const float sw2r = s2[lane];
  const float sb2v = sb[0];
  float gs1 = 0.f, gs2 = 0.f;
  float* zw = &zS[wv][0];
  const int wid = blockIdx.x * 4 + wv, nw = gridDim.x * 4;
  for (int p = wid; p < PTS; p += nw) {
    const size_t abase = (size_t)p * 1024 + r16 * 64 + q4 * 8;
    const half8 xa0 = *(const half8*)(xbuf + abase);
    const half8 xa1 = *(const half8*)(xbuf + abase + 32);
#pragma unroll
    for (int t = 0; t < 4; ++t) {
      f32x4 acc = {0.f, 0.f, 0.f, 0.f};
      acc = __builtin_amdgcn_mfma_f32_16x16x32_f16(xa0, b2[t * 2], acc, 0, 0, 0);
      acc = __builtin_amdgcn_mfma_f32_16x16x32_f16(xa1, b2[t * 2 + 1], acc, 0, 0, 0);
#pragma unroll
      for (int rr = 0; rr < 4; ++rr)
        zw[(q4 * 4 + rr) * 64 + t * 16 + r16] = acc[rr];
    }
    wavefence();
    const __half* xr = xbuf + (size_t)p * 1024 + lane;
    const float* zr = zw + lane;
    float xv[16], pl[16];
#pragma unroll
    for (int k = 0; k < 16; ++k) {
      xv[k] = __half2float(xr[k * 64]);
      float h = (zr[k * 64] - zm) * zsc;
      h = h > 0.f ? h : 0.f;
      pl[k] = h * sw2r;
    }
#pragma unroll
    for (int off = 1; off < 64; off <<= 1) {
#pragma unroll
      for (int k = 0; k < 16; ++k) pl[k] += __shfl_xor(pl[k], off, 64);
    }
    float mx = -FLT_MAX;
#pragma unroll
    for (int k = 0; k < 16; ++k) { pl[k] += sb2v; mx = fmaxf(mx, pl[k]); }
    float se = 0.f;
#pragma unroll
    for (int k = 0; k < 16; ++k) { pl[k] = expf(pl[k] - mx); se += pl[k]; }
    const float inv = 1.f / se;
    float f = 0.f;
#pragma unroll
    for (int k = 0; k < 16; ++k) f += xv[k] * (pl[k] * inv);
    featL[wv][lane] = f;
    wavefence();
    const float* featW = &featL[wv][0];
    float g0 = 0.f, g1 = 0.f, g2 = 0.f, g3 = 0.f;
#pragma unroll
    for (int c8 = 0; c8 < 8; ++c8) {
      const float4 fa = *(const float4*)(featW + c8 * 8);
      const float4 fb = *(const float4*)(featW + c8 * 8 + 4);
      const __half2 m0 = mrow[c8 * 4 + 0];
      const __half2 m1 = mrow[c8 * 4 + 1];
      const __half2 m2 = mrow[c8 * 4 + 2];
      const __half2 m3 = mrow[c8 * 4 + 3];
      g0 += fa.x * __low2float(m0); g1 += fa.y * __high2float(m0);
      g2 += fa.z * __low2float(m1); g3 += fa.w * __high2float(m1);
      g0 += fb.x * __low2float(m2); g1 += fb.y * __high2float(m2);
      g2 += fb.z * __low2float(m3); g3 += fb.w * __high2float(m3);
    }
    const float g = (g0 + g1) + (g2 + g3);
    graw[((size_t)br * PTS + p) * 64 + lane] = g;
    gs1 += g; gs2 += g * g;
    wavefence();  // zS reuse next iteration
  }
  atomicAdd(&dstat[DS_G + br * 64 + lane], (double)gs1);
  atomicAdd(&dstat[DS_G + 128 + br * 64 + lane], (double)gs2);
}

// ---------------- legacy passA/passB (fallback if workspace too small) ------
__global__ __launch_bounds__(256)
void passA_kernel(const float* __restrict__ xyz,
                  const float* __restrict__ features,
                  const int* __restrict__ idx,
                  const float* __restrict__ wl1,
                  const float* __restrict__ wl2,
                  const float* __restrict__ s1a,
                  const float* __restrict__ s1b,
                  const float* __restrict__ bnp,
                  double* __restrict__ dstat) {
  const int br = blockIdx.y;
  const float* W = br ? wl2 : wl1;
  const float* S1 = br ? s1b : s1a;
  __shared__ __align__(16) __half encS[4][16 * 40];
  __shared__ __align__(16) __half xS[4][16 * 64];
  const int lane = threadIdx.x & 63, wv = threadIdx.x >> 6;
  __half* enc = encS[wv];
  __half* xL = xS[wv];
  zero_enc_pad(enc, lane);
  wavefence();
  __half2 wh2[20];
  load_w40(W + lane * 36, wh2);
  __half2 sh2[32];
#pragma unroll
  for (int c = 0; c < 32; ++c)
    sh2[c] = __floats2half2_rn(S1[lane * 64 + 2 * c], S1[lane * 64 + 2 * c + 1]);
  const float ym = bnp[DS_Y + br * 64 + lane];
  const float ys = bnp[DS_Y + 128 + br * 64 + lane];
  float zs1 = 0.f, zs2 = 0.f;
  const int wid = blockIdx.x * 4 + wv, nw = gridDim.x * 4;
  GATHER_PROLOGUE
#pragma unroll
    for (int k = 0; k < 16; ++k) {
      float xv = (dot40h(enc + k * 40, wh2) - ym) * ys;
      xv = xv > 0.f ? xv : 0.f;
      xL[k * 64 + lane] = __float2half(xv);
    }
    wavefence();
#pragma unroll
    for (int k = 0; k < 16; ++k) {
      const float acc = dot64x(xL + k * 64, sh2);
      zs1 += acc; zs2 += acc * acc;
    }
  GATHER_EPILOGUE
  atomicAdd(&dstat[DS_Z + br * 64 + lane], (double)zs1);
  atomicAdd(&dstat[DS_Z + 128 + br * 64 + lane], (double)zs2);
}

__global__ __launch_bounds__(256)
void passB_kernel(const float* __restrict__ xyz,
                  const float* __restrict__ features,
                  const int* __restrict__ idx,
                  const float* __restrict__ wl1,
                  const float* __restrict__ wl2,
                  const float* __restrict__ s1a,
                  const float* __restrict__ s1b,
                  const float* __restrict__ s2a,
                  const float* __restrict__ s2b,
                  const float* __restrict__ sba,
                  const float* __restrict__ sbb,
                  const float* __restrict__ mwa,
                  const float* __restrict__ mwb,
                  const float* __restrict__ bnp,
                  double* __restrict__ dstat,
                  float* __restrict__ graw) {
  const int br = blockIdx.y;
  const float* W = br ? wl2 : wl1;
  const float* S1 = br ? s1b : s1a;
  const float* S2 = br ? s2b : s2a;
  const float* SB = br ? sbb : sba;
  const float* MW = br ? mwb : mwa;
  __shared__ __align__(16) __half2 mwl2[64 * 34];
  __shared__ __align__(16) __half encS[4][16 * 40];
  __shared__ __align__(16) __half xS[4][16 * 64];
  __shared__ __align__(16) float featL[4][64];
  for (int t = threadIdx.x; t < 64 * 32; t += 256) {
    const int r = t >> 5, c2 = t & 31;
    mwl2[r * 34 + c2] = __floats2half2_rn(MW[r * 64 + c2 * 2], MW[r * 64 + c2 * 2 + 1]);
  }
  __syncthreads();
  const int lane = threadIdx.x & 63, wv = threadIdx.x >> 6;
  __half* enc = encS[wv];
  __half* xL = xS[wv];
  zero_enc_pad(enc, lane);
  wavefence();
  const __half2* mrow = mwl2 + lane * 34;
  __half2 wh2[20];
  load_w40(W + lane * 36, wh2);
  __half2 sh2[32];
#pragma unroll
  for (int c = 0; c < 32; ++c)
    sh2[c] = __floats2half2_rn(S1[lane * 64 + 2 * c], S1[lane * 64 + 2 * c + 1]);
  const float ym = bnp[DS_Y + br * 64 + lane];
  const float ys = bnp[DS_Y + 128 + br * 64 + lane];
  const float zm = bnp[DS_Z + br * 64 + lane];
  const float zs = bnp[DS_Z + 128 + br * 64 + lane];
  const float sw2r = S2[lane];
  const float sb2v = SB[0];
  float gs1 = 0.f, gs2 = 0.f;
  const int wid = blockIdx.x * 4 + wv, nw = gridDim.x * 4;
  GATHER_PROLOGUE
#pragma unroll
    for (int k = 0; k < 16; ++k) {
      float xv = (dot40h(enc + k * 40, wh2) - ym) * ys;
      xv = xv > 0.f ? xv : 0.f;
      xL[k * 64 + lane] = __float2half(xv);
    }
    wavefence();
    float pl[16];
#pragma unroll
    for (int k = 0; k < 16; ++k) {
      float h = (dot64x(xL + k * 64, sh2) - zm) * zs;
      h = h > 0.f ? h : 0.f;
      pl[k] = h * sw2r;
    }
#pragma unroll
    for (int off = 1; off < 64; off <<= 1) {
#pragma unroll
      for (int k = 0; k < 16; ++k) pl[k] += __shfl_xor(pl[k], off, 64);
    }
    float mx = -FLT_MAX;
#pragma unroll
    for (int k = 0; k < 16; ++k) { pl[k] += sb2v; mx = fmaxf(mx, pl[k]); }
    float se = 0.f;
#pragma unroll
    for (int k = 0; k < 16; ++k) { pl[k] = expf(pl[k] - mx); se += pl[k]; }
    const float inv = 1.f / se;
    float f = 0.f;
#pragma unroll
    for (int k = 0; k < 16; ++k) f += __half2float(xL[k * 64 + lane]) * (pl[k] * inv);
    featL[wv][lane] = f;
    wavefence();
    const float* featW = &featL[wv][0];
    float g0 = 0.f, g1 = 0.f, g2 = 0.f, g3 = 0.f;
#pragma unroll
    for (int c8 = 0; c8 < 8; ++c8) {
      const float4 fa = *(const float4*)(featW + c8 * 8);
      const float4 fb = *(const float4*)(featW + c8 * 8 + 4);
      const __half2 m0 = mrow[c8 * 4 + 0];
      const __half2 m1 = mrow[c8 * 4 + 1];
      const __half2 m2 = mrow[c8 * 4 + 2];
      const __half2 m3 = mrow[c8 * 4 + 3];
      g0 += fa.x * __low2float(m0); g1 += fa.y * __high2float(m0);
      g2 += fa.z * __low2float(m1); g3 += fa.w * __high2float(m1);
      g0 += fb.x * __low2float(m2); g1 += fb.y * __high2float(m2);
      g2 += fb.z * __low2float(m3); g3 += fb.w * __high2float(m3);
    }
    const float g = (g0 + g1) + (g2 + g3);
    graw[((size_t)br * PTS + p) * 64 + lane] = g;
    gs1 += g; gs2 += g * g;
  GATHER_EPILOGUE
  atomicAdd(&dstat[DS_G + br * 64 + lane], (double)gs1);
  atomicAdd(&dstat[DS_G + 128 + br * 64 + lane], (double)gs2);
}

// ---------------- DRB matmul stage (128x128 per-point matvec + stats) -------
__global__ __launch_bounds__(256) void drb_mm_kernel(const float* __restrict__ in,
                                                     const float* __restrict__ wmat,
                                                     const float* __restrict__ bnp,
                                                     double* __restrict__ dstat,
                                                     float* __restrict__ aggout,
                                                     float* __restrict__ rowout,
                                                     int bpIn, int dsOut, int mode) {
  __shared__ __align__(16) float wlds[128 * 129];
  __shared__ __align__(16) float rowS[4][128];
  for (int t = threadIdx.x; t < 128 * 128; t += 256) wlds[(t >> 7) * 129 + (t & 127)] = wmat[t];
  __syncthreads();  // one-time weight staging only
  const int lane = threadIdx.x & 63, wv = threadIdx.x >> 6;
  const float m0 = bnp[bpIn + lane], s0 = bnp[bpIn + 128 + lane];
  const float m1 = bnp[bpIn + 64 + lane], s1 = bnp[bpIn + 128 + 64 + lane];
  float a1s0 = 0.f, a1s1 = 0.f, a2s0 = 0.f, a2s1 = 0.f;
  const int wid = blockIdx.x * 4 + wv, nw = gridDim.x * 4;
  for (int p = wid; p < PTS; p += nw) {
    float v0, v1;
    if (mode == 0) {  // input = g_raw [2][PTS][64]
      v0 = in[(size_t)p * 64 + lane];
      v1 = in[(size_t)PTS * 64 + (size_t)p * 64 + lane];
    } else {          // input = h1 raw [PTS][128]
      v0 = in[(size_t)p * 128 + lane];
      v1 = in[(size_t)p * 128 + 64 + lane];
    }
    v0 = (v0 - m0) * s0; v0 = v0 > 0.f ? v0 : 0.f;
    v1 = (v1 - m1) * s1; v1 = v1 > 0.f ? v1 : 0.f;
    rowS[wv][lane] = v0;
    rowS[wv][64 + lane] = v1;
    if (aggout) {
      aggout[(size_t)p * 128 + lane] = v0;
      aggout[(size_t)p * 128 + 64 + lane] = v1;
    }
    wavefence();
#pragma unroll
    for (int h = 0; h < 2; ++h) {
      const int o = h * 64 + lane;
      float b0 = 0.f, b1 = 0.f, b2 = 0.f, b3 = 0.f;
#pragma unroll
      for (int c4 = 0; c4 < 32; ++c4) {
        const float4 rv = *(const float4*)(&rowS[wv][c4 * 4]);
        b0 += rv.x * wlds[o * 129 + c4 * 4 + 0];
        b1 += rv.y * wlds[o * 129 + c4 * 4 + 1];
        b2 += rv.z * wlds[o * 129 + c4 * 4 + 2];
        b3 += rv.w * wlds[o * 129 + c4 * 4 + 3];
      }
      const float acc = (b0 + b1) + (b2 + b3);
      rowout[(size_t)p * 128 + o] = acc;
      if (h == 0) { a1s0 += acc; a2s0 += acc * acc; }
      else        { a1s1 += acc; a2s1 += acc * acc; }
    }
    wavefence();
  }
  atomicAdd(&dstat[dsOut + lane], (double)a1s0);
  atomicAdd(&dstat[dsOut + 64 + lane], (double)a1s1);
  atomicAdd(&dstat[dsOut + 128 + lane], (double)a2s0);
  atomicAdd(&dstat[dsOut + 128 + 64 + lane], (double)a2s1);
}

// ---------------- final: out = relu(bn(h2) + agg) ---------------------------
__global__ __launch_bounds__(256) void final_kernel(const float* __restrict__ h2,
                                                    const float* __restrict__ agg,
                                                    const float* __restrict__ bnp,
                                                    float* __restrict__ out) {
  const size_t e = (size_t)blockIdx.x * 256 + threadIdx.x;
  const int ch = (int)(e & 127);
  const float m = bnp[DS_H2 + ch], s = bnp[DS_H2 + 128 + ch];
  float v = (h2[e] - m) * s + agg[e];
  out[e] = v > 0.f ? v : 0.f;
}

extern "C" void kernel_launch(void* const* d_in, const int* in_sizes, int n_in,
                              void* d_out, int out_size, void* d_ws, size_t ws_size,
                              hipStream_t stream) {
  (void)in_sizes; (void)n_in; (void)out_size;
  const float* xyz      = (const float*)d_in[0];
  const float* features = (const float*)d_in[1];
  const float* w_lse1   = (const float*)d_in[2];
  const float* w_lse2   = (const float*)d_in[3];
  const float* ap1_sw1  = (const float*)d_in[4];
  const float* ap1_sw2  = (const float*)d_in[5];
  const float* ap1_sb2  = (const float*)d_in[6];
  const float* ap1_mw   = (const float*)d_in[7];
  const float* ap2_sw1  = (const float*)d_in[8];
  const float* ap2_sw2  = (const float*)d_in[9];
  const float* ap2_sb2  = (const float*)d_in[10];
  const float* ap2_mw   = (const float*)d_in[11];
  const float* drb_w1   = (const float*)d_in[12];
  const float* drb_w2   = (const float*)d_in[13];

  char* ws = (char*)d_ws;
  const bool mat = (ws_size >= WS_NEED);

  float*  knn_d = (float*)(ws + OFF_KD);
  int*    knn_j = (int*)(ws + OFF_KJ);
  int*    idx   = (int*)(ws + (mat ? OFF_IDX : FB_IDX));
  double* dstat = (double*)(ws + (mat ? OFF_DST : FB_DST));
  float*  mstat = (float*)(ws + (mat ? OFF_MST : FB_MST));
  float*  bnp   = (float*)(ws + (mat ? OFF_BNP : FB_BNP));
  float*  graw  = (float*)(ws + (mat ? OFF_GRAW : FB_GRAW));
  float*  agg   = (float*)(ws + (mat ? OFF_AGG : FB_AGG));
  float*  h1    = (float*)(ws + (mat ? OFF_H1 : FB_H1));
  float*  h2    = (float*)(ws + (mat ? OFF_H2 : FB_H2));
  float*  out   = (float*)d_out;

  // zero dstat (1280 doubles) + mstat (36*37 floats, contiguous after)
  (void)hipMemsetAsync(dstat, 0, 1280 * sizeof(double) + 36 * 37 * sizeof(float), stream);

  knn_chunk_kernel<<<dim3(Nq / 256, CH, Bq), 256, 0, stream>>>(xyz, knn_d, knn_j);
  knn_merge_kernel<<<dim3(PTS / 256), 256, 0, stream>>>(knn_d, knn_j, idx);

  __half* encb = mat ? (__half*)(ws + OFF_ENC) : nullptr;
  encM_kernel<<<dim3(1280), 256, 0, stream>>>(xyz, features, idx, mstat, encb);
  y_finalize_kernel<<<1, 128, 0, stream>>>(mstat, w_lse1, w_lse2, bnp);

  if (mat) {
    __half* x0 = (__half*)(ws + OFF_X0);   // overlays dead knn_d/knn_j
    __half* x1 = (__half*)(ws + OFF_X1);
    passA2s_kernel<<<dim3(1024), 256, 0, stream>>>(encb, w_lse1, w_lse2, bnp, x0, x1);
    zstat_kernel<<<dim3(1024), 256, 0, stream>>>(x0, x1, ap1_sw1, ap2_sw1, dstat);
    bn_finalize_kernel<<<1, 128, 0, stream>>>(dstat, bnp, DS_Z, 1.0 / ROWS);
    passB2_mat_kernel<<<dim3(1024), 256, 0, stream>>>(x0, ap1_sw1, ap1_sw2, ap1_sb2,
                                                      ap1_mw, bnp, dstat, graw, 0);
    passB2_mat_kernel<<<dim3(1024), 256, 0, stream>>>(x1, ap2_sw1, ap2_sw2, ap2_sb2,
                                                      ap2_mw, bnp, dstat, graw, 1);
  } else {
    // legacy fallback (workspace too small for materialization)
    passA_kernel<<<dim3(640, 2), 256, 0, stream>>>(xyz, features, idx, w_lse1, w_lse2,
                                                   ap1_sw1, ap2_sw1, bnp, dstat);
    bn_finalize_kernel<<<1, 128, 0, stream>>>(dstat, bnp, DS_Z, 1.0 / ROWS);
    passB_kernel<<<dim3(512, 2), 256, 0, stream>>>(xyz, features, idx, w_lse1, w_lse2,
                                                   ap1_sw1, ap2_sw1, ap1_sw2, ap2_sw2,
                                                   ap1_sb2, ap2_sb2, ap1_mw, ap2_mw,
                                                   bnp, dstat, graw);
  }
  bn_finalize_kernel<<<1, 128, 0, stream>>>(dstat, bnp, DS_G, 1.0 / PTS);

  drb_mm_kernel<<<dim3(512), 256, 0, stream>>>(graw, drb_w1, bnp, dstat, agg, h1,
                                               DS_G, DS_H1, 0);
  bn_finalize_kernel<<<1, 128, 0, stream>>>(dstat, bnp, DS_H1, 1.0 / PTS);

  drb_mm_kernel<<<dim3(512), 256, 0, stream>>>(h1, drb_w2, bnp, dstat, nullptr, h2,
                                               DS_H1, DS_H2, 1);
  bn_finalize_kernel<<<1, 128, 0, stream>>>(dstat, bnp, DS_H2, 1.0 / PTS);

  final_kernel<<<dim3(PTS * 128 / 256), 256, 0, stream>>>(h2, agg, bnp, out);
}

// Round 8
// 1180.634 us; speedup vs baseline: 1.0804x; 1.0804x over previous
//
#include <hip/hip_runtime.h>
#include <hip/hip_bf16.h>
#include <hip/hip_fp16.h>
#include <float.h>
#include <math.h>

#define DEVFN __device__ __forceinline__

// Compiler-only fence: wave64 executes DS ops in order; stops reordering.
DEVFN void wavefence() { __builtin_amdgcn_wave_barrier(); }

using half8 = __attribute__((ext_vector_type(8))) _Float16;
using f32x4 = __attribute__((ext_vector_type(4))) float;

namespace {
constexpr int Bq = 4, Nq = 8192, Cq = 32, Kq = 16;
constexpr int PTS = Bq * Nq;          // 32768 points
constexpr int CH = 16;                 // knn candidate chunks
constexpr int CAND = Nq / CH;          // 512 candidates per chunk
constexpr double ROWS = 524288.0;      // PTS * Kq

// dstat/bnp region bases (each region: [sum|mean x128][sumsq|scale x128])
constexpr int DS_Y = 0, DS_Z = 256, DS_G = 512, DS_H1 = 768, DS_H2 = 1024;

// ---- workspace layout (proven-available 228 MiB) ----
// time-disjoint: knn_d/kj [0,64) -> x0 [0,64) -> h1/h2 [0,32) (drb stage).
// x1 [64,128). enc [128,168) (written by encM, read by passA2s).
constexpr size_t OFF_KD   = 0;                          // knn_d 32MB
constexpr size_t OFF_KJ   = (size_t)32 << 20;           // knn_j 32MB
constexpr size_t OFF_X0   = 0;                          // x br0 f16 64MB
constexpr size_t OFF_X1   = (size_t)64 << 20;           // x br1 f16 64MB
constexpr size_t OFF_ENC  = (size_t)128 << 20;          // enc f16 [PTS][16][40] = 40MB
constexpr size_t OFF_H1   = 0;                          // h1 raw 16MB (x0 dead by drb)
constexpr size_t OFF_H2   = (size_t)16 << 20;           // h2 raw 16MB
constexpr size_t OFF_GRAW = (size_t)192 << 20;          // graw 16MB
constexpr size_t OFF_AGG  = (size_t)208 << 20;          // agg 16MB
constexpr size_t OFF_IDX  = (size_t)224 << 20;          // idx 2MB
constexpr size_t OFF_DST  = (size_t)226 << 20;          // dstat (1280 doubles)
constexpr size_t OFF_MST  = ((size_t)226 << 20) + 10240;
constexpr size_t OFF_BNP  = ((size_t)226 << 20) + 16384;
constexpr size_t WS_NEED  = ((size_t)226 << 20) + 32768;
// compact fallback layout (legacy path) for small workspaces
constexpr size_t FB_GRAW  = (size_t)64 << 20;
constexpr size_t FB_AGG   = (size_t)80 << 20;
constexpr size_t FB_H1    = (size_t)96 << 20;
constexpr size_t FB_H2    = (size_t)112 << 20;
constexpr size_t FB_IDX   = (size_t)128 << 20;
constexpr size_t FB_DST   = (size_t)130 << 20;
constexpr size_t FB_MST   = ((size_t)130 << 20) + 10240;
constexpr size_t FB_BNP   = ((size_t)130 << 20) + 16384;
}

// ---------------- KNN: batched bitonic top-16 ------------------------------
DEVFN void ce_asc(float& a, float& b) {
  const float lo = fminf(a, b), hi = fmaxf(a, b);
  a = lo; b = hi;
}

DEVFN void topk16_update(float* __restrict__ L, float* __restrict__ d) {
  // canonical ascending bitonic sort of d[0..15]
#pragma unroll
  for (int k = 2; k <= 16; k <<= 1) {
#pragma unroll
    for (int j = k >> 1; j > 0; j >>= 1) {
#pragma unroll
      for (int i = 0; i < 16; ++i) {
        const int l = i ^ j;
        if (l > i) {
          if ((i & k) == 0) {
            const float lo = fminf(d[i], d[l]), hi = fmaxf(d[i], d[l]);
            d[i] = lo; d[l] = hi;
          } else {
            const float lo = fminf(d[i], d[l]), hi = fmaxf(d[i], d[l]);
            d[i] = hi; d[l] = lo;
          }
        }
      }
    }
  }
  // fold: lowest-16 of L (asc) U d (asc) -> L bitonic
#pragma unroll
  for (int i = 0; i < 16; ++i) L[i] = fminf(L[i], d[15 - i]);
  // bitonic clean back to ascending
#pragma unroll
  for (int j = 8; j > 0; j >>= 1) {
#pragma unroll
    for (int i = 0; i < 16; ++i) {
      const int l = i ^ j;
      if (l > i) ce_asc(L[i], L[l]);
    }
  }
}

DEVFN float distf(const float4 c, const float qx, const float qy, const float qz) {
  const float dx = qx - c.x, dy = qy - c.y, dz = qz - c.z;
  return __fadd_rn(__fadd_rn(__fmul_rn(dx, dx), __fmul_rn(dy, dy)), __fmul_rn(dz, dz));
}

__global__ __launch_bounds__(256, 4) void knn_chunk_kernel(const float* __restrict__ xyz,
                                                           float* __restrict__ pd,
                                                           int* __restrict__ pj) {
  const int b = blockIdx.z;
  const int ch = blockIdx.y;
  const int n = blockIdx.x * 256 + threadIdx.x;
  __shared__ __align__(16) float4 tile[CAND];
  const float* xb = xyz + (size_t)b * Nq * 3;
  for (int t = threadIdx.x; t < CAND; t += 256) {
    const int j = ch * CAND + t;
    tile[t] = make_float4(xb[j * 3], xb[j * 3 + 1], xb[j * 3 + 2], 0.f);
  }
  __syncthreads();
  const float qx = xb[n * 3], qy = xb[n * 3 + 1], qz = xb[n * 3 + 2];
  float L[16];
#pragma unroll
  for (int i = 0; i < 16; ++i) L[i] = FLT_MAX;
  for (int t = 0; t < CAND; t += 16) {
    float d[16];
#pragma unroll
    for (int u = 0; u < 16; ++u) d[u] = distf(tile[t + u], qx, qy, qz);
    topk16_update(L, d);
  }
  const float kth = L[15];
  const size_t base = (((size_t)b * Nq + n) * CH + ch) * Kq;
  int cnt = 0, tfirst = -1;
  for (int t = 0; t < CAND; ++t) {
    const float d = distf(tile[t], qx, qy, qz);
    if (d < kth) { pd[base + cnt] = d; pj[base + cnt] = ch * CAND + t; ++cnt; }
    tfirst = (d == kth && tfirst < 0) ? t : tfirst;
  }
  if (cnt == 15) {  // typical (all-distinct): exactly one kth tie -> done
    pd[base + 15] = kth; pj[base + 15] = ch * CAND + tfirst; cnt = 16;
  }
  if (__any(cnt < 16)) {  // rare multi-tie fallback (exactness)
    for (int t = 0; t < CAND; ++t) {
      const float d = distf(tile[t], qx, qy, qz);
      if (d == kth && cnt < 16) { pd[base + cnt] = d; pj[base + cnt] = ch * CAND + t; ++cnt; }
    }
  }
}

__global__ __launch_bounds__(256, 4) void knn_merge_kernel(const float* __restrict__ pd,
                                                           const int* __restrict__ pj,
                                                           int* __restrict__ idxo) {
  const int q = blockIdx.x * 256 + threadIdx.x;
  const float* dp = pd + (size_t)q * CH * Kq;
  const int* jp = pj + (size_t)q * CH * Kq;
  float L[16];
#pragma unroll
  for (int i = 0; i < 16; ++i) L[i] = FLT_MAX;
  for (int t = 0; t < CH * Kq; t += 16) {
    float d[16];
#pragma unroll
    for (int u = 0; u < 16; u += 4) {
      const float4 v = *(const float4*)(dp + t + u);
      d[u] = v.x; d[u + 1] = v.y; d[u + 2] = v.z; d[u + 3] = v.w;
    }
    topk16_update(L, d);
  }
  const float kth = L[15];
  int* op = idxo + (size_t)q * Kq;
  int cnt = 0;
  for (int t = 0; t < CH * Kq; ++t) {
    const float d = dp[t];
    if (d < kth) { op[cnt] = jp[t]; ++cnt; }
  }
  for (int t = 0; t < CH * Kq; ++t) {
    const float d = dp[t];
    if (d == kth && cnt < 16) { op[cnt] = jp[t]; ++cnt; }
  }
}

// ---------------- gather pipeline pieces ------------------------------------
struct PF { float4 f0, f1; float nx, ny, nz; };

DEVFN PF issue_feat(const float* __restrict__ features, const float* __restrict__ xyz,
                    int p, int j, int sub) {
  const int b = p >> 13;
  const float* fr = features + ((size_t)b * Nq + j) * Cq;
  const float* xb = xyz + ((size_t)b * Nq + j) * 3;
  PF r;
  r.f0 = *(const float4*)(fr + sub * 8);
  r.f1 = *(const float4*)(fr + sub * 8 + 4);
  r.nx = xb[0]; r.ny = xb[1]; r.nz = xb[2];
  return r;
}

DEVFN int issue_idx(const int* __restrict__ idx, int p, int lane) {
  return idx[(size_t)p * Kq + (lane >> 2)];
}

DEVFN float3 issue_query(const float* __restrict__ xyz, int p) {
  const float* q = xyz + (size_t)p * 3;  // [B,N,3] flat: p = b*Nq+n
  return make_float3(q[0], q[1], q[2]);
}

// legacy enc row layout (f16, STORED-space, 40h = 80B/row)
DEVFN void commit_enc(__half* __restrict__ enc, int lane, const PF& pf,
                      float qx, float qy, float qz) {
  const int k = lane >> 2, sub = lane & 3;
  __half* er = enc + k * 40;
  union { float4 f; __half2 h[4]; } u;
  u.h[0] = __floats2half2_rn(pf.f0.x, pf.f0.y);
  u.h[1] = __floats2half2_rn(pf.f0.z, pf.f0.w);
  u.h[2] = __floats2half2_rn(pf.f1.x, pf.f1.y);
  u.h[3] = __floats2half2_rn(pf.f1.z, pf.f1.w);
  *(float4*)(er + sub * 8) = u.f;    // byte 80k+16*sub: 16B aligned
  if (sub == 0) {
    const float rx = pf.nx - qx, ry = pf.ny - qy, rz = pf.nz - qz;
    const float ss = rx * rx + ry * ry + rz * rz;
    const float dd = sqrtf(fmaxf(ss, 1e-12f));
    __half2* rd = (__half2*)(er + 32);
    rd[0] = __floats2half2_rn(rx, ry);
    rd[1] = __floats2half2_rn(rz, dd);
  }
}

// zero the 4 pad halves of each of the wave's 16 rows (legacy 40h layout).
DEVFN void zero_enc_pad(__half* __restrict__ enc, int lane) {
  if (lane < 16) {
    const __half2 z2 = __floats2half2_rn(0.f, 0.f);
    __half2* pz = (__half2*)(enc + lane * 40 + 36);
    pz[0] = z2; pz[1] = z2;
  }
}

// dot(enc_row (40 f16), wh2[20]) -- legacy fallback path.
DEVFN float dot40h(const __half* __restrict__ er, const __half2* __restrict__ wh2) {
  float a0 = 0.f, a1 = 0.f, a2 = 0.f, a3 = 0.f;
#pragma unroll
  for (int r = 0; r < 5; ++r) {
    union { float4 f; __half2 h[4]; } u;
    u.f = *(const float4*)(er + r * 8);
#pragma unroll
    for (int q = 0; q < 4; ++q) {
      const __half2 xv = u.h[q];
      const __half2 wv = wh2[r * 4 + q];
      if (q & 1) {
        a2 += __low2float(xv) * __low2float(wv);
        a3 += __high2float(xv) * __high2float(wv);
      } else {
        a0 += __low2float(xv) * __low2float(wv);
        a1 += __high2float(xv) * __high2float(wv);
      }
    }
  }
  return (a0 + a1) + (a2 + a3);
}

// dot(x_row (64 f16), sh2[32]) -- legacy fallback path.
DEVFN float dot64x(const __half* __restrict__ xr, const __half2* __restrict__ sh2) {
  float a0 = 0.f, a1 = 0.f, a2 = 0.f, a3 = 0.f;
#pragma unroll
  for (int r = 0; r < 8; ++r) {
    union { float4 f; __half2 h[4]; } u;
    u.f = *(const float4*)(xr + r * 8);
#pragma unroll
    for (int q = 0; q < 4; ++q) {
      const __half2 xv = u.h[q];
      const __half2 wv = sh2[r * 4 + q];
      if (q & 1) {
        a2 += __low2float(xv) * __low2float(wv);
        a3 += __high2float(xv) * __high2float(wv);
      } else {
        a0 += __low2float(xv) * __low2float(wv);
        a1 += __high2float(xv) * __high2float(wv);
      }
    }
  }
  return (a0 + a1) + (a2 + a3);
}

// load lane's 36 weights (original order) into STORED-space f16 pairs.
DEVFN void load_w40(const float* __restrict__ Wrow, __half2* wh2) {
#pragma unroll
  for (int c = 0; c < 16; ++c)
    wh2[c] = __floats2half2_rn(Wrow[4 + 2 * c], Wrow[5 + 2 * c]);
  wh2[16] = __floats2half2_rn(Wrow[0], Wrow[1]);
  wh2[17] = __floats2half2_rn(Wrow[2], Wrow[3]);
  wh2[18] = __floats2half2_rn(0.f, 0.f);
  wh2[19] = wh2[18];
}

// MFMA B-fragments. B[k][n] layout: col n = lane&15 (+tile*16),
// k = (lane>>4)*8 + j (+kstep*32). Layer1: k = STORED enc dim (pad>=36 zero).
DEVFN void load_b1(const float* __restrict__ W, int lane, half8* b1) {
  const int o16 = lane & 15, q = lane >> 4;
#pragma unroll
  for (int t = 0; t < 4; ++t) {
    const int o = t * 16 + o16;
#pragma unroll
    for (int ks = 0; ks < 2; ++ks) {
      half8 v;
#pragma unroll
      for (int j = 0; j < 8; ++j) {
        const int s = ks * 32 + q * 8 + j;
        float wv = 0.f;
        if (s < 36) { const int orig = (s < 32) ? (s + 4) : (s - 32); wv = W[o * 36 + orig]; }
        v[j] = (_Float16)wv;
      }
      b1[t * 2 + ks] = v;
    }
  }
}

DEVFN void load_b2(const float* __restrict__ S1, int lane, half8* b2) {
  const int o16 = lane & 15, q = lane >> 4;
#pragma unroll
  for (int t = 0; t < 4; ++t) {
    const int o = t * 16 + o16;
#pragma unroll
    for (int ks = 0; ks < 2; ++ks) {
      half8 v;
#pragma unroll
      for (int j = 0; j < 8; ++j) {
        const int c = ks * 32 + q * 8 + j;
        v[j] = (_Float16)S1[o * 64 + c];
      }
      b2[t * 2 + ks] = v;
    }
  }
}

// pipeline open/close macros (body sits between them as ordinary code).
#define GATHER_PROLOGUE                                                      \
  int p = wid;                                                               \
  int jc = issue_idx(idx, p, lane);                                          \
  PF cur = issue_feat(features, xyz, p, jc, lane & 3);                       \
  float3 qc = issue_query(xyz, p);                                           \
  int pn0 = p + nw; if (pn0 >= PTS) pn0 = p;                                 \
  int jn = issue_idx(idx, pn0, lane);                                        \
  float3 qn = issue_query(xyz, pn0);                                         \
  for (; p < PTS; p += nw) {                                                 \
    int pn = p + nw; if (pn >= PTS) pn = p;                                  \
    int pn2 = pn + nw; if (pn2 >= PTS) pn2 = pn;                             \
    PF nxt = issue_feat(features, xyz, pn, jn, lane & 3);                    \
    const int jn2 = issue_idx(idx, pn2, lane);                               \
    const float3 q2 = issue_query(xyz, pn2);                                 \
    commit_enc(enc, lane, cur, qc.x, qc.y, qc.z);                            \
    wavefence();

#define GATHER_EPILOGUE                                                      \
    wavefence();                                                             \
    cur = nxt; qc = qn; qn = q2; jn = jn2;                                   \
  }

// ---------------- encM: moments + (mat path) enc copy-out -------------------
__global__ __launch_bounds__(256) void encM_kernel(const float* __restrict__ xyz,
                                                   const float* __restrict__ features,
                                                   const int* __restrict__ idx,
                                                   float* __restrict__ mstat,
                                                   __half* __restrict__ encb) {
  __shared__ __align__(16) __half encS[4][16 * 40];
  __shared__ float mred[4][36 * 37];
  const int lane = threadIdx.x & 63, wv = threadIdx.x >> 6;
  __half* enc = encS[wv];
  zero_enc_pad(enc, lane);
  wavefence();
  const int li = (lane < 36) ? lane : 0;  // clamp: lanes>=36 compute junk, never stored
  float macc[36];
#pragma unroll
  for (int i = 0; i < 36; ++i) macc[i] = 0.f;
  float vacc = 0.f;
  const int wid = blockIdx.x * 4 + wv, nw = gridDim.x * 4;
  GATHER_PROLOGUE
#pragma unroll
    for (int k = 0; k < 16; ++k) {
      const __half* er = enc + k * 40;
      const float ei = __half2float(er[li]);
      vacc += ei;
#pragma unroll
      for (int r = 0; r < 5; ++r) {
        union { float4 f; __half2 h[4]; } u;
        u.f = *(const float4*)(er + r * 8);
#pragma unroll
        for (int q = 0; q < 4; ++q) {
          const int s = r * 8 + 2 * q;
          if (s < 36)     macc[s]     += ei * __low2float(u.h[q]);
          if (s + 1 < 36) macc[s + 1] += ei * __high2float(u.h[q]);
        }
      }
    }
    if (encb) {  // 1280B linear copy: LDS byte c*16 -> global p*1280 + c*16
#pragma unroll
      for (int it = 0; it < 2; ++it) {
        const int c = it * 64 + lane;
        if (c < 80) {
          const float4 v = *(const float4*)((const char*)enc + c * 16);
          *(float4*)((char*)encb + (size_t)p * 1280 + c * 16) = v;
        }
      }
    }
  GATHER_EPILOGUE
  if (lane < 36) {
#pragma unroll
    for (int j = 0; j < 36; ++j) mred[wv][lane * 37 + j] = macc[j];
    mred[wv][lane * 37 + 36] = vacc;
  }
  __syncthreads();
  for (int t = threadIdx.x; t < 36 * 37; t += 256) {
    const float s = mred[0][t] + mred[1][t] + mred[2][t] + mred[3][t];
    atomicAdd(&mstat[t], s);
  }
}

// y-stat finalize from STORED-space moments.
__global__ void y_finalize_kernel(const float* __restrict__ mstat,
                                  const float* __restrict__ wl1,
                                  const float* __restrict__ wl2,
                                  float* __restrict__ bnp) {
  const int t = threadIdx.x;  // 128
  const int br = t >> 6, o = t & 63;
  const float* W = br ? wl2 : wl1;
  double wrow[36];
  for (int s = 0; s < 36; ++s) {
    const int orig = (s < 32) ? (s + 4) : (s - 32);
    wrow[s] = (double)W[o * 36 + orig];
  }
  double mean = 0.0, ey2 = 0.0;
  for (int i = 0; i < 36; ++i) {
    mean += wrow[i] * (double)mstat[i * 37 + 36];
    double rowacc = 0.0;
    for (int j = 0; j < 36; ++j) rowacc += wrow[j] * (double)mstat[i * 37 + j];
    ey2 += wrow[i] * rowacc;
  }
  const double invR = 1.0 / ROWS;
  mean *= invR; ey2 *= invR;
  const double var = ey2 - mean * mean;
  bnp[DS_Y + br * 64 + o] = (float)mean;
  bnp[DS_Y + 128 + br * 64 + o] = (float)(1.0 / sqrt(var + 1e-5));
}

// ---------------- generic BN stat finalize: mean + rsqrt(var+eps) -----------
__global__ void bn_finalize_kernel(const double* __restrict__ dstat, float* __restrict__ bnp,
                                   int base, double invc) {
  const int t = threadIdx.x;  // 128 threads
  const double m = dstat[base + t] * invc;
  const double v = dstat[base + 128 + t] * invc - m * m;
  bnp[base + t] = (float)m;
  bnp[base + 128 + t] = (float)(1.0 / sqrt(v + 1e-5));
}

// ---------------- passA2s: enc -> y (MFMA, both br) -> x0,x1 + z-stats ------
// Streaming (no gather). Also accumulates z BN stats inline (z = x @ S1^T via
// MFMA from the LDS-staged x -- same f16 bits the old zstat kernel used, so
// stats are identical modulo double-atomic order).
__global__ __launch_bounds__(256)
void passA2s_kernel(const __half* __restrict__ encbuf,
                    const float* __restrict__ wl1,
                    const float* __restrict__ wl2,
                    const float* __restrict__ s1a,
                    const float* __restrict__ s1b,
                    const float* __restrict__ bnp,
                    double* __restrict__ dstat,
                    __half* __restrict__ x0buf,
                    __half* __restrict__ x1buf) {
  __shared__ __align__(16) __half xS[4][16 * 64];
  const int lane = threadIdx.x & 63, wv = threadIdx.x >> 6;
  __half* xL = xS[wv];
  half8 b1a[8], b1b[8], b2a[8], b2b[8];
  load_b1(wl1, lane, b1a);
  load_b1(wl2, lane, b1b);
  load_b2(s1a, lane, b2a);
  load_b2(s1b, lane, b2b);
  const int r16 = lane & 15, q4 = lane >> 4;
  float ym0[4], ys0[4], ym1[4], ys1[4];
#pragma unroll
  for (int t = 0; t < 4; ++t) {
    ym0[t] = bnp[DS_Y + t * 16 + r16];
    ys0[t] = bnp[DS_Y + 128 + t * 16 + r16];
    ym1[t] = bnp[DS_Y + 64 + t * 16 + r16];
    ys1[t] = bnp[DS_Y + 128 + 64 + t * 16 + r16];
  }
  float sa1[4] = {0.f, 0.f, 0.f, 0.f}, sa2[4] = {0.f, 0.f, 0.f, 0.f};
  float sb1[4] = {0.f, 0.f, 0.f, 0.f}, sb2s[4] = {0.f, 0.f, 0.f, 0.f};
  const int wid = blockIdx.x * 4 + wv, nw = gridDim.x * 4;
  for (int p = wid; p < PTS; p += nw) {
    const size_t eb = (size_t)p * 640 + r16 * 40 + q4 * 8;
    const half8 a0 = *(const half8*)(encbuf + eb);
    half8 a1;
#pragma unroll
    for (int j = 0; j < 8; ++j) a1[j] = (_Float16)0.f;
    if (q4 == 0) a1 = *(const half8*)(encbuf + eb + 32);
    // ---- branch 0 ----
    {
      f32x4 yt[4];
#pragma unroll
      for (int t = 0; t < 4; ++t) {
        f32x4 acc = {0.f, 0.f, 0.f, 0.f};
        acc = __builtin_amdgcn_mfma_f32_16x16x32_f16(a0, b1a[t * 2], acc, 0, 0, 0);
        acc = __builtin_amdgcn_mfma_f32_16x16x32_f16(a1, b1a[t * 2 + 1], acc, 0, 0, 0);
        yt[t] = acc;
      }
#pragma unroll
      for (int t = 0; t < 4; ++t) {
        const int col = t * 16 + r16;
        const int chk = col >> 3;
#pragma unroll
        for (int rr = 0; rr < 4; ++rr) {
          const int row = q4 * 4 + rr;
          float xv = (yt[t][rr] - ym0[t]) * ys0[t];
          xv = xv > 0.f ? xv : 0.f;
          *(_Float16*)((char*)xL + row * 128 + ((chk ^ (row & 7)) * 16) + (col & 7) * 2) =
              (_Float16)xv;
        }
      }
      wavefence();
#pragma unroll
      for (int it = 0; it < 2; ++it) {
        const int chunk = it * 64 + lane;
        const int row = chunk >> 3, c8 = chunk & 7;
        const float4 xv4 = *(const float4*)((const char*)xL + row * 128 + ((c8 ^ (row & 7)) * 16));
        *(float4*)((char*)x0buf + (size_t)p * 2048 + chunk * 16) = xv4;
      }
      // z-stats (br0): A-frags from the swizzled xL
      const char* xlb = (const char*)xL + r16 * 128;
      const half8 xa0 = *(const half8*)(xlb + (((q4)     ^ (r16 & 7)) * 16));
      const half8 xa1 = *(const half8*)(xlb + (((4 + q4) ^ (r16 & 7)) * 16));
#pragma unroll
      for (int t = 0; t < 4; ++t) {
        f32x4 acc = {0.f, 0.f, 0.f, 0.f};
        acc = __builtin_amdgcn_mfma_f32_16x16x32_f16(xa0, b2a[t * 2], acc, 0, 0, 0);
        acc = __builtin_amdgcn_mfma_f32_16x16x32_f16(xa1, b2a[t * 2 + 1], acc, 0, 0, 0);
#pragma unroll
        for (int rr = 0; rr < 4; ++rr) { const float zv = acc[rr]; sa1[t] += zv; sa2[t] += zv * zv; }
      }
      wavefence();   // all xL reads done before br1 overwrites
    }
    // ---- branch 1 ----
    {
      f32x4 yt[4];
#pragma unroll
      for (int t = 0; t < 4; ++t) {
        f32x4 acc = {0.f, 0.f, 0.f, 0.f};
        acc = __builtin_amdgcn_mfma_f32_16x16x32_f16(a0, b1b[t * 2], acc, 0, 0, 0);
        acc = __builtin_amdgcn_mfma_f32_16x16x32_f16(a1, b1b[t * 2 + 1], acc, 0, 0, 0);
        yt[t] = acc;
      }
#pragma unroll
      for (int t = 0; t < 4; ++t) {
        const int col = t * 16 + r16;
        const int chk = col >> 3;
#pragma unroll
        for (int rr = 0; rr < 4; ++rr) {
          const int row = q4 * 4 + rr;
          float xv = (yt[t][rr] - ym1[t]) * ys1[t];
          xv = xv > 0.f ? xv : 0.f;
          *(_Float16*)((char*)xL + row * 128 + ((chk ^ (row & 7)) * 16) + (col & 7) * 2) =
              (_Float16)xv;
        }
      }
      wavefence();
#pragma unroll
      for (int it = 0; it < 2; ++it) {
        const int chunk = it * 64 + lane;
        const int row = chunk >> 3, c8 = chunk & 7;
        const float4 xv4 = *(const float4*)((const char*)xL + row * 128 + ((c8 ^ (row & 7)) * 16));
        *(float4*)((char*)x1buf + (size_t)p * 2048 + chunk * 16) = xv4;
      }
      // z-stats (br1)
      const char* xlb = (const char*)xL + r16 * 128;
      const half8 xb0 = *(const half8*)(xlb + (((q4)     ^ (r16 & 7)) * 16));
      const half8 xb1 = *(const half8*)(xlb + (((4 + q4) ^ (r16 & 7)) * 16));
#pragma unroll
      for (int t = 0; t < 4; ++t) {
        f32x4 acc = {0.f, 0.f, 0.f, 0.f};
        acc = __builtin_amdgcn_mfma_f32_16x16x32_f16(xb0, b2b[t * 2], acc, 0, 0, 0);
        acc = __builtin_amdgcn_mfma_f32_16x16x32_f16(xb1, b2b[t * 2 + 1], acc, 0, 0, 0);
#pragma unroll
        for (int rr = 0; rr < 4; ++rr) { const float zv = acc[rr]; sb1[t] += zv; sb2s[t] += zv * zv; }
      }
      wavefence();   // xL reuse next iteration
    }
  }
  // reduce stats: C-layout col = t*16 + r16, rows spread over q4 groups
#pragma unroll
  for (int t = 0; t < 4; ++t) {
    sa1[t] += __shfl_xor(sa1[t], 16, 64);  sa1[t] += __shfl_xor(sa1[t], 32, 64);
    sa2[t] += __shfl_xor(sa2[t], 16, 64);  sa2[t] += __shfl_xor(sa2[t], 32, 64);
    sb1[t] += __shfl_xor(sb1[t], 16, 64);  sb1[t] += __shfl_xor(sb1[t], 32, 64);
    sb2s[t] += __shfl_xor(sb2s[t], 16, 64); sb2s[t] += __shfl_xor(sb2s[t], 32, 64);
  }
  if (lane < 16) {
#pragma unroll
    for (int t = 0; t < 4; ++t) {
      atomicAdd(&dstat[DS_Z + t * 16 + lane], (double)sa1[t]);
      atomicAdd(&dstat[DS_Z + 128 + t * 16 + lane], (double)sa2[t]);
      atomicAdd(&dstat[DS_Z + 64 + t * 16 + lane], (double)sb1[t]);
      atomicAdd(&dstat[DS_Z + 128 + 64 + t * 16 + lane], (double)sb2s[t]);
    }
  }
}

// ---------------- passB2: read x, recompute z via MFMA -> LDS, then softmax -
// Merged both branches into one launch (blockIdx.y = br) for full packing.
__global__ __launch_bounds__(256)
void passB2_mat_kernel(const __half* __restrict__ x0,
                       const __half* __restrict__ x1,
                       const float* __restrict__ s1a,
                       const float* __restrict__ s1b,
                       const float* __restrict__ s2a,
                       const float* __restrict__ s2b,
                       const float* __restrict__ sba,
                       const float* __restrict__ sbb,
                       const float* __restrict__ mwa,
                       const float* __restrict__ mwb,
                       const float* __restrict__ bnp,
                       double* __restrict__ dstat,
                       float* __restrict__ graw) {
  const int br = blockIdx.y;
  const __half* xbuf = br ? x1 : x0;
  const float* S1 = br ? s1b : s1a;
  const float* s2 = br ? s2b : s2a;
  const float* sb = br ? sbb : sba;
  const float* mw = br ? mwb : mwa;
  __shared__ __align__(16) __half2 mwl2[64 * 34];  // row stride 34 pairs
  __shared__ __align__(16) float featL[4][64];
  __shared__ __align__(16) float zS[4][16 * 64];
  for (int t = threadIdx.x; t < 64 * 32; t += 256) {
    const int r = t >> 5, c2 = t & 31;
    mwl2[r * 34 + c2] = __floats2half2_rn(mw[r * 64 + c2 * 2], mw[r * 64 + c2 * 2 + 1]);
  }
  __syncthreads();  // one-time weight staging only
  const int lane = threadIdx.x & 63, wv = threadIdx.x >> 6;
  const int r16 = lane & 15, q4 = lane >> 4;
  half8 b2[8];
  load_b2(S1, lane, b2);
  const __half2* mrow = mwl2 + lane * 34;
  const float zm = bnp[DS_Z + br * 64 + lane];
  const float zsc = bnp[DS_Z + 128 + br * 64 + lane];
  const float sw2r = s2[lane];
  const float sb2v = sb[0];
  float gs1 = 0.f, gs2 = 0.f;
  float* zw = &zS[wv][0];
  const int wid = blockIdx.x * 4 + wv, nw = gridDim.x * 4;
  for (int p = wid; p < PTS; p += nw) {
    const size_t abase = (size_t)p * 1024 + r16 * 64 + q4 * 8;
    const half8 xa0 = *(const half8*)(xbuf + abase);
    const half8 xa1 = *(const half8*)(xbuf + abase + 32);
#pragma unroll
    for (int t = 0; t < 4; ++t) {
      f32x4 acc = {0.f, 0.f, 0.f, 0.f};
      acc = __builtin_amdgcn_mfma_f32_16x16x32_f16(xa0, b2[t * 2], acc, 0, 0, 0);
      acc = __builtin_amdgcn_mfma_f32_16x16x32_f16(xa1, b2[t * 2 + 1], acc, 0, 0, 0);
#pragma unroll
      for (int rr = 0; rr < 4; ++rr)
        zw[(q4 * 4 + rr) * 64 + t * 16 + r16] = acc[rr];
    }
    wavefence();
    const __half* xr = xbuf + (size_t)p * 1024 + lane;
    const float* zr = zw + lane;
    float xv[16], pl[16];
#pragma unroll
    for (int k = 0; k < 16; ++k) {
      xv[k] = __half2float(xr[k * 64]);
      float h = (zr[k * 64] - zm) * zsc;
      h = h > 0.f ? h : 0.f;
      pl[k] = h * sw2r;
    }
#pragma unroll
    for (int off = 1; off < 64; off <<= 1) {
#pragma unroll
      for (int k = 0; k < 16; ++k) pl[k] += __shfl_xor(pl[k], off, 64);
    }
    float mx = -FLT_MAX;
#pragma unroll
    for (int k = 0; k < 16; ++k) { pl[k] += sb2v; mx = fmaxf(mx, pl[k]); }
    float se = 0.f;
#pragma unroll
    for (int k = 0; k < 16; ++k) { pl[k] = expf(pl[k] - mx); se += pl[k]; }
    const float inv = 1.f / se;
    float f = 0.f;
#pragma unroll
    for (int k = 0; k < 16; ++k) f += xv[k] * (pl[k] * inv);
    featL[wv][lane] = f;
    wavefence();
    const float* featW = &featL[wv][0];
    float g0 = 0.f, g1 = 0.f, g2 = 0.f, g3 = 0.f;
#pragma unroll
    for (int c8 = 0; c8 < 8; ++c8) {
      const float4 fa = *(const float4*)(featW + c8 * 8);
      const float4 fb = *(const float4*)(featW + c8 * 8 + 4);
      const __half2 m0 = mrow[c8 * 4 + 0];
      const __half2 m1 = mrow[c8 * 4 + 1];
      const __half2 m2 = mrow[c8 * 4 + 2];
      const __half2 m3 = mrow[c8 * 4 + 3];
      g0 += fa.x * __low2float(m0); g1 += fa.y * __high2float(m0);
      g2 += fa.z * __low2float(m1); g3 += fa.w * __high2float(m1);
      g0 += fb.x * __low2float(m2); g1 += fb.y * __high2float(m2);
      g2 += fb.z * __low2float(m3); g3 += fb.w * __high2float(m3);
    }
    const float g = (g0 + g1) + (g2 + g3);
    graw[((size_t)br * PTS + p) * 64 + lane] = g;
    gs1 += g; gs2 += g * g;
    wavefence();  // zS reuse next iteration
  }
  atomicAdd(&dstat[DS_G + br * 64 + lane], (double)gs1);
  atomicAdd(&dstat[DS_G + 128 + br * 64 + lane], (double)gs2);
}

// ---------------- legacy passA/passB (fallback if workspace too small) ------
__global__ __launch_bounds__(256)
void passA_kernel(const float* __restrict__ xyz,
                  const float* __restrict__ features,
                  const int* __restrict__ idx,
                  const float* __restrict__ wl1,
                  const float* __restrict__ wl2,
                  const float* __restrict__ s1a,
                  const float* __restrict__ s1b,
                  const float* __restrict__ bnp,
                  double* __restrict__ dstat) {
  const int br = blockIdx.y;
  const float* W = br ? wl2 : wl1;
  const float* S1 = br ? s1b : s1a;
  __shared__ __align__(16) __half encS[4][16 * 40];
  __shared__ __align__(16) __half xS[4][16 * 64];
  const int lane = threadIdx.x & 63, wv = threadIdx.x >> 6;
  __half* enc = encS[wv];
  __half* xL = xS[wv];
  zero_enc_pad(enc, lane);
  wavefence();
  __half2 wh2[20];
  load_w40(W + lane * 36, wh2);
  __half2 sh2[32];
#pragma unroll
  for (int c = 0; c < 32; ++c)
    sh2[c] = __floats2half2_rn(S1[lane * 64 + 2 * c], S1[lane * 64 + 2 * c + 1]);
  const float ym = bnp[DS_Y + br * 64 + lane];
  const float ys = bnp[DS_Y + 128 + br * 64 + lane];
  float zs1 = 0.f, zs2 = 0.f;
  const int wid = blockIdx.x * 4 + wv, nw = gridDim.x * 4;
  GATHER_PROLOGUE
#pragma unroll
    for (int k = 0; k < 16; ++k) {
      float xv = (dot40h(enc + k * 40, wh2) - ym) * ys;
      xv = xv > 0.f ? xv : 0.f;
      xL[k * 64 + lane] = __float2half(xv);
    }
    wavefence();
#pragma unroll
    for (int k = 0; k < 16; ++k) {
      const float acc = dot64x(xL + k * 64, sh2);
      zs1 += acc; zs2 += acc * acc;
    }
  GATHER_EPILOGUE
  atomicAdd(&dstat[DS_Z + br * 64 + lane], (double)zs1);
  atomicAdd(&dstat[DS_Z + 128 + br * 64 + lane], (double)zs2);
}

__global__ __launch_bounds__(256)
void passB_kernel(const float* __restrict__ xyz,
                  const float* __restrict__ features,
                  const int* __restrict__ idx,
                  const float* __restrict__ wl1,
                  const float* __restrict__ wl2,
                  const float* __restrict__ s1a,
                  const float* __restrict__ s1b,
                  const float* __restrict__ s2a,
                  const float* __restrict__ s2b,
                  const float* __restrict__ sba,
                  const float* __restrict__ sbb,
                  const float* __restrict__ mwa,
                  const float* __restrict__ mwb,
                  const float* __restrict__ bnp,
                  double* __restrict__ dstat,
                  float* __restrict__ graw) {
  const int br = blockIdx.y;
  const float* W = br ? wl2 : wl1;
  const float* S1 = br ? s1b : s1a;
  const float* S2 = br ? s2b : s2a;
  const float* SB = br ? sbb : sba;
  const float* MW = br ? mwb : mwa;
  __shared__ __align__(16) __half2 mwl2[64 * 34];
  __shared__ __align__(16) __half encS[4][16 * 40];
  __shared__ __align__(16) __half xS[4][16 * 64];
  __shared__ __align__(16) float featL[4][64];
  for (int t = threadIdx.x; t < 64 * 32; t += 256) {
    const int r = t >> 5, c2 = t & 31;
    mwl2[r * 34 + c2] = __floats2half2_rn(MW[r * 64 + c2 * 2], MW[r * 64 + c2 * 2 + 1]);
  }
  __syncthreads();
  const int lane = threadIdx.x & 63, wv = threadIdx.x >> 6;
  __half* enc = encS[wv];
  __half* xL = xS[wv];
  zero_enc_pad(enc, lane);
  wavefence();
  const __half2* mrow = mwl2 + lane * 34;
  __half2 wh2[20];
  load_w40(W + lane * 36, wh2);
  __half2 sh2[32];
#pragma unroll
  for (int c = 0; c < 32; ++c)
    sh2[c] = __floats2half2_rn(S1[lane * 64 + 2 * c], S1[lane * 64 + 2 * c + 1]);
  const float ym = bnp[DS_Y + br * 64 + lane];
  const float ys = bnp[DS_Y + 128 + br * 64 + lane];
  const float zm = bnp[DS_Z + br * 64 + lane];
  const float zs = bnp[DS_Z + 128 + br * 64 + lane];
  const float sw2r = S2[lane];
  const float sb2v = SB[0];
  float gs1 = 0.f, gs2 = 0.f;
  const int wid = blockIdx.x * 4 + wv, nw = gridDim.x * 4;
  GATHER_PROLOGUE
#pragma unroll
    for (int k = 0; k < 16; ++k) {
      float xv = (dot40h(enc + k * 40, wh2) - ym) * ys;
      xv = xv > 0.f ? xv : 0.f;
      xL[k * 64 + lane] = __float2half(xv);
    }
    wavefence();
    float pl[16];
#pragma unroll
    for (int k = 0; k < 16; ++k) {
      float h = (dot64x(xL + k * 64, sh2) - zm) * zs;
      h = h > 0.f ? h : 0.f;
      pl[k] = h * sw2r;
    }
#pragma unroll
    for (int off = 1; off < 64; off <<= 1) {
#pragma unroll
      for (int k = 0; k < 16; ++k) pl[k] += __shfl_xor(pl[k], off, 64);
    }
    float mx = -FLT_MAX;
#pragma unroll
    for (int k = 0; k < 16; ++k) { pl[k] += sb2v; mx = fmaxf(mx, pl[k]); }
    float se = 0.f;
#pragma unroll
    for (int k = 0; k < 16; ++k) { pl[k] = expf(pl[k] - mx); se += pl[k]; }
    const float inv = 1.f / se;
    float f = 0.f;
#pragma unroll
    for (int k = 0; k < 16; ++k) f += __half2float(xL[k * 64 + lane]) * (pl[k] * inv);
    featL[wv][lane] = f;
    wavefence();
    const float* featW = &featL[wv][0];
    float g0 = 0.f, g1 = 0.f, g2 = 0.f, g3 = 0.f;
#pragma unroll
    for (int c8 = 0; c8 < 8; ++c8) {
      const float4 fa = *(const float4*)(featW + c8 * 8);
      const float4 fb = *(const float4*)(featW + c8 * 8 + 4);
      const __half2 m0 = mrow[c8 * 4 + 0];
      const __half2 m1 = mrow[c8 * 4 + 1];
      const __half2 m2 = mrow[c8 * 4 + 2];
      const __half2 m3 = mrow[c8 * 4 + 3];
      g0 += fa.x * __low2float(m0); g1 += fa.y * __high2float(m0);
      g2 += fa.z * __low2float(m1); g3 += fa.w * __high2float(m1);
      g0 += fb.x * __low2float(m2); g1 += fb.y * __high2float(m2);
      g2 += fb.z * __low2float(m3); g3 += fb.w * __high2float(m3);
    }
    const float g = (g0 + g1) + (g2 + g3);
    graw[((size_t)br * PTS + p) * 64 + lane] = g;
    gs1 += g; gs2 += g * g;
  GATHER_EPILOGUE
  atomicAdd(&dstat[DS_G + br * 64 + lane], (double)gs1);
  atomicAdd(&dstat[DS_G + 128 + br * 64 + lane], (double)gs2);
}

// ---------------- DRB matmul stage (128x128 per-point matvec + stats) -------
__global__ __launch_bounds__(256) void drb_mm_kernel(const float* __restrict__ in,
                                                     const float* __restrict__ wmat,
                                                     const float* __restrict__ bnp,
                                                     double* __restrict__ dstat,
                                                     float* __restrict__ aggout,
                                                     float* __restrict__ rowout,
                                                     int bpIn, int dsOut, int mode) {
  __shared__ __align__(16) float wlds[128 * 129];
  __shared__ __align__(16) float rowS[4][128];
  for (int t = threadIdx.x; t < 128 * 128; t += 256) wlds[(t >> 7) * 129 + (t & 127)] = wmat[t];
  __syncthreads();  // one-time weight staging only
  const int lane = threadIdx.x & 63, wv = threadIdx.x >> 6;
  const float m0 = bnp[bpIn + lane], s0 = bnp[bpIn + 128 + lane];
  const float m1 = bnp[bpIn + 64 + lane], s1 = bnp[bpIn + 128 + 64 + lane];
  float a1s0 = 0.f, a1s1 = 0.f, a2s0 = 0.f, a2s1 = 0.f;
  const int wid = blockIdx.x * 4 + wv, nw = gridDim.x * 4;
  for (int p = wid; p < PTS; p += nw) {
    float v0, v1;
    if (mode == 0) {  // input = g_raw [2][PTS][64]
      v0 = in[(size_t)p * 64 + lane];
      v1 = in[(size_t)PTS * 64 + (size_t)p * 64 + lane];
    } else {          // input = h1 raw [PTS][128]
      v0 = in[(size_t)p * 128 + lane];
      v1 = in[(size_t)p * 128 + 64 + lane];
    }
    v0 = (v0 - m0) * s0; v0 = v0 > 0.f ? v0 : 0.f;
    v1 = (v1 - m1) * s1; v1 = v1 > 0.f ? v1 : 0.f;
    rowS[wv][lane] = v0;
    rowS[wv][64 + lane] = v1;
    if (aggout) {
      aggout[(size_t)p * 128 + lane] = v0;
      aggout[(size_t)p * 128 + 64 + lane] = v1;
    }
    wavefence();
#pragma unroll
    for (int h = 0; h < 2; ++h) {
      const int o = h * 64 + lane;
      float b0 = 0.f, b1 = 0.f, b2 = 0.f, b3 = 0.f;
#pragma unroll
      for (int c4 = 0; c4 < 32; ++c4) {
        const float4 rv = *(const float4*)(&rowS[wv][c4 * 4]);
        b0 += rv.x * wlds[o * 129 + c4 * 4 + 0];
        b1 += rv.y * wlds[o * 129 + c4 * 4 + 1];
        b2 += rv.z * wlds[o * 129 + c4 * 4 + 2];
        b3 += rv.w * wlds[o * 129 + c4 * 4 + 3];
      }
      const float acc = (b0 + b1) + (b2 + b3);
      rowout[(size_t)p * 128 + o] = acc;
      if (h == 0) { a1s0 += acc; a2s0 += acc * acc; }
      else        { a1s1 += acc; a2s1 += acc * acc; }
    }
    wavefence();
  }
  atomicAdd(&dstat[dsOut + lane], (double)a1s0);
  atomicAdd(&dstat[dsOut + 64 + lane], (double)a1s1);
  atomicAdd(&dstat[dsOut + 128 + lane], (double)a2s0);
  atomicAdd(&dstat[dsOut + 128 + 64 + lane], (double)a2s1);
}

// ---------------- final: out = relu(bn(h2) + agg) ---------------------------
__global__ __launch_bounds__(256) void final_kernel(const float* __restrict__ h2,
                                                    const float* __restrict__ agg,
                                                    const float* __restrict__ bnp,
                                                    float* __restrict__ out) {
  const size_t e = (size_t)blockIdx.x * 256 + threadIdx.x;
  const int ch = (int)(e & 127);
  const float m = bnp[DS_H2 + ch], s = bnp[DS_H2 + 128 + ch];
  float v = (h2[e] - m) * s + agg[e];
  out[e] = v > 0.f ? v : 0.f;
}

extern "C" void kernel_launch(void* const* d_in, const int* in_sizes, int n_in,
                              void* d_out, int out_size, void* d_ws, size_t ws_size,
                              hipStream_t stream) {
  (void)in_sizes; (void)n_in; (void)out_size;
  const float* xyz      = (const float*)d_in[0];
  const float* features = (const float*)d_in[1];
  const float* w_lse1   = (const float*)d_in[2];
  const float* w_lse2   = (const float*)d_in[3];
  const float* ap1_sw1  = (const float*)d_in[4];
  const float* ap1_sw2  = (const float*)d_in[5];
  const float* ap1_sb2  = (const float*)d_in[6];
  const float* ap1_mw   = (const float*)d_in[7];
  const float* ap2_sw1  = (const float*)d_in[8];
  const float* ap2_sw2  = (const float*)d_in[9];
  const float* ap2_sb2  = (const float*)d_in[10];
  const float* ap2_mw   = (const float*)d_in[11];
  const float* drb_w1   = (const float*)d_in[12];
  const float* drb_w2   = (const float*)d_in[13];

  char* ws = (char*)d_ws;
  const bool mat = (ws_size >= WS_NEED);

  float*  knn_d = (float*)(ws + OFF_KD);
  int*    knn_j = (int*)(ws + OFF_KJ);
  int*    idx   = (int*)(ws + (mat ? OFF_IDX : FB_IDX));
  double* dstat = (double*)(ws + (mat ? OFF_DST : FB_DST));
  float*  mstat = (float*)(ws + (mat ? OFF_MST : FB_MST));
  float*  bnp   = (float*)(ws + (mat ? OFF_BNP : FB_BNP));
  float*  graw  = (float*)(ws + (mat ? OFF_GRAW : FB_GRAW));
  float*  agg   = (float*)(ws + (mat ? OFF_AGG : FB_AGG));
  float*  h1    = (float*)(ws + (mat ? OFF_H1 : FB_H1));
  float*  h2    = (float*)(ws + (mat ? OFF_H2 : FB_H2));
  float*  out   = (float*)d_out;

  // zero dstat (1280 doubles) + mstat (36*37 floats, contiguous after)
  (void)hipMemsetAsync(dstat, 0, 1280 * sizeof(double) + 36 * 37 * sizeof(float), stream);

  knn_chunk_kernel<<<dim3(Nq / 256, CH, Bq), 256, 0, stream>>>(xyz, knn_d, knn_j);
  knn_merge_kernel<<<dim3(PTS / 256), 256, 0, stream>>>(knn_d, knn_j, idx);

  __half* encb = mat ? (__half*)(ws + OFF_ENC) : nullptr;
  encM_kernel<<<dim3(1280), 256, 0, stream>>>(xyz, features, idx, mstat, encb);
  y_finalize_kernel<<<1, 128, 0, stream>>>(mstat, w_lse1, w_lse2, bnp);

  if (mat) {
    __half* x0 = (__half*)(ws + OFF_X0);   // overlays dead knn_d/knn_j
    __half* x1 = (__half*)(ws + OFF_X1);
    passA2s_kernel<<<dim3(1024), 256, 0, stream>>>(encb, w_lse1, w_lse2,
                                                   ap1_sw1, ap2_sw1, bnp, dstat, x0, x1);
    bn_finalize_kernel<<<1, 128, 0, stream>>>(dstat, bnp, DS_Z, 1.0 / ROWS);
    passB2_mat_kernel<<<dim3(1024, 2), 256, 0, stream>>>(x0, x1, ap1_sw1, ap2_sw1,
                                                         ap1_sw2, ap2_sw2, ap1_sb2, ap2_sb2,
                                                         ap1_mw, ap2_mw, bnp, dstat, graw);
  } else {
    // legacy fallback (workspace too small for materialization)
    passA_kernel<<<dim3(640, 2), 256, 0, stream>>>(xyz, features, idx, w_lse1, w_lse2,
                                                   ap1_sw1, ap2_sw1, bnp, dstat);
    bn_finalize_kernel<<<1, 128, 0, stream>>>(dstat, bnp, DS_Z, 1.0 / ROWS);
    passB_kernel<<<dim3(512, 2), 256, 0, stream>>>(xyz, features, idx, w_lse1, w_lse2,
                                                   ap1_sw1, ap2_sw1, ap1_sw2, ap2_sw2,
                                                   ap1_sb2, ap2_sb2, ap1_mw, ap2_mw,
                                                   bnp, dstat, graw);
  }
  bn_finalize_kernel<<<1, 128, 0, stream>>>(dstat, bnp, DS_G, 1.0 / PTS);

  drb_mm_kernel<<<dim3(512), 256, 0, stream>>>(graw, drb_w1, bnp, dstat, agg, h1,
                                               DS_G, DS_H1, 0);
  bn_finalize_kernel<<<1, 128, 0, stream>>>(dstat, bnp, DS_H1, 1.0 / PTS);

  drb_mm_kernel<<<dim3(512), 256, 0, stream>>>(h1, drb_w2, bnp, dstat, nullptr, h2,
                                               DS_H1, DS_H2, 1);
  bn_finalize_kernel<<<1, 128, 0, stream>>>(dstat, bnp, DS_H2, 1.0 / PTS);

  final_kernel<<<dim3(PTS * 128 / 256), 256, 0, stream>>>(h2, agg, bnp, out);
}